// Round 5
// baseline (275.967 us; speedup 1.0000x reference)
//
#include <hip/hip_runtime.h>

typedef unsigned short u16;
typedef __bf16 bf16x8 __attribute__((ext_vector_type(8)));
typedef float f32x4 __attribute__((ext_vector_type(4)));

#define MFMA(a, b, c) __builtin_amdgcn_mfma_f32_16x16x32_bf16((a), (b), (c), 0, 0, 0)

__device__ __forceinline__ u16 f2bf(float f) {
    unsigned u = __float_as_uint(f);
    unsigned r = (u + 0x7fffu + ((u >> 16) & 1u)) >> 16;  // RNE
    return (u16)r;
}
__device__ __forceinline__ float bf2f(u16 h) { return __uint_as_float(((unsigned)h) << 16); }

typedef unsigned int u32_g __attribute__((address_space(1)));
typedef unsigned int u32_l __attribute__((address_space(3)));
__device__ __forceinline__ void gload16(const void* g, void* l) {
    __builtin_amdgcn_global_load_lds((const u32_g*)g, (u32_l*)l, 16, 0, 0);
}

// ---------------------------------------------------------------------------
// Shapes: b=16, c=256, n=4096, heads=8, dim_head=32
// Gram-trick pipeline, LN+Gram fused: G = X.X^T accumulated via fp32 atomics.
// ---------------------------------------------------------------------------

// K1: fused LayerNorm + Gram partial.  grid = 16 b * 32 chunks = 512, block = 1024.
// Thread (np = t&63 -> n pair, cg = t>>6 = wave -> 16 c rows).
// LDS: one 64 KB buffer, time-shared: [stats redS/redS2/mu/rs] then [xst bf16 tile].
// xst layout: [c][np] u32 pairs with slot-XOR swizzle: 4-dword slot s at
// dword (c*64 + ((s ^ (c&15))<<2)) -> conflict-free writes AND frag reads.
__global__ __launch_bounds__(1024) void k_lngram(const float* __restrict__ x,
                                                 const float* __restrict__ gamma,
                                                 const float* __restrict__ beta,
                                                 u16* __restrict__ xlnT, float* __restrict__ Gf) {
    __shared__ __align__(16) unsigned smem[256 * 64];  // 64 KB
    float* sf = (float*)smem;
    int bid = blockIdx.x;
    int b = bid >> 5, ch = bid & 31;
    int nb = ch * 128;
    int t = threadIdx.x;
    int np = t & 63, cg = t >> 6;
    // P1: load 16 c-rows x 2 n, partial stats
    const float* xp = x + ((size_t)(b * 256 + cg * 16)) * 4096 + nb + np * 2;
    float2 v[16];
    float s0 = 0.f, s1 = 0.f, s20 = 0.f, s21 = 0.f;
#pragma unroll
    for (int i = 0; i < 16; i++) {
        float2 f = *(const float2*)(xp + (size_t)i * 4096);
        v[i] = f;
        s0 += f.x; s20 += f.x * f.x;
        s1 += f.y; s21 += f.y * f.y;
    }
    sf[cg * 128 + 2 * np] = s0;
    sf[cg * 128 + 2 * np + 1] = s1;
    sf[2048 + cg * 128 + 2 * np] = s20;
    sf[2048 + cg * 128 + 2 * np + 1] = s21;
    __syncthreads();
    // P2: finalize stats for 128 n
    if (t < 128) {
        float s = 0.f, s2 = 0.f;
#pragma unroll
        for (int g = 0; g < 16; g++) { s += sf[g * 128 + t]; s2 += sf[2048 + g * 128 + t]; }
        float m = s * (1.f / 256.f);
        float var = s2 * (1.f / 256.f) - m * m;
        sf[4096 + t] = m;
        sf[4224 + t] = rsqrtf(var + 1e-5f);
    }
    __syncthreads();
    float m0 = sf[4096 + 2 * np], r0 = sf[4224 + 2 * np];
    float m1 = sf[4096 + 2 * np + 1], r1 = sf[4224 + 2 * np + 1];
    __syncthreads();  // all mu/rs reads done before xst overwrites smem
    // P3: normalize in regs, write xst (swizzled) + xlnT global
    u16 hA[16], hB[16];
    int sw = ((np >> 2) ^ (cg & 15));  // note: (c&15) varies with i below; recompute per i
#pragma unroll
    for (int i = 0; i < 16; i++) {
        int c = cg * 16 + i;
        float g = gamma[c], e = beta[c];
        float a = (v[i].x - m0) * r0 * g + e;
        float bv = (v[i].y - m1) * r1 * g + e;
        u16 ha = f2bf(a), hb = f2bf(bv);
        hA[i] = ha; hB[i] = hb;
        int dw = c * 64 + ((((np >> 2) ^ (c & 15)) << 2) | (np & 3));
        smem[dw] = (unsigned)ha | ((unsigned)hb << 16);
    }
    (void)sw;
    {
        u16* dst0 = xlnT + ((size_t)(b * 4096 + nb + 2 * np)) * 256 + cg * 16;
        uint4 qa, qb;
        qa.x = (unsigned)hA[0] | ((unsigned)hA[1] << 16);
        qa.y = (unsigned)hA[2] | ((unsigned)hA[3] << 16);
        qa.z = (unsigned)hA[4] | ((unsigned)hA[5] << 16);
        qa.w = (unsigned)hA[6] | ((unsigned)hA[7] << 16);
        qb.x = (unsigned)hA[8] | ((unsigned)hA[9] << 16);
        qb.y = (unsigned)hA[10] | ((unsigned)hA[11] << 16);
        qb.z = (unsigned)hA[12] | ((unsigned)hA[13] << 16);
        qb.w = (unsigned)hA[14] | ((unsigned)hA[15] << 16);
        *(uint4*)dst0 = qa;
        *(uint4*)(dst0 + 8) = qb;
        u16* dst1 = dst0 + 256;
        qa.x = (unsigned)hB[0] | ((unsigned)hB[1] << 16);
        qa.y = (unsigned)hB[2] | ((unsigned)hB[3] << 16);
        qa.z = (unsigned)hB[4] | ((unsigned)hB[5] << 16);
        qa.w = (unsigned)hB[6] | ((unsigned)hB[7] << 16);
        qb.x = (unsigned)hB[8] | ((unsigned)hB[9] << 16);
        qb.y = (unsigned)hB[10] | ((unsigned)hB[11] << 16);
        qb.z = (unsigned)hB[12] | ((unsigned)hB[13] << 16);
        qb.w = (unsigned)hB[14] | ((unsigned)hB[15] << 16);
        *(uint4*)dst1 = qa;
        *(uint4*)(dst1 + 8) = qb;
    }
    __syncthreads();
    // P4: Gram MFMA. wave w: m-frag rows {mr2, mr2+1}, n-frags nf0..nf0+7.
    {
        int lane = t & 63, l15 = lane & 15, quad = lane >> 4;
        int w = t >> 6;
        int mr2 = (w & 7) * 2, nf0 = (w >> 3) * 8;
        f32x4 acc[2][8];
        f32x4 z = {0.f, 0.f, 0.f, 0.f};
        for (int fm = 0; fm < 2; fm++)
            for (int j = 0; j < 8; j++) acc[fm][j] = z;
#pragma unroll
        for (int ks = 0; ks < 4; ks++) {
            int ca0 = (mr2 * 16 + l15);
            int ca1 = ((mr2 + 1) * 16 + l15);
            bf16x8 a0 = *(const bf16x8*)&smem[ca0 * 64 + (((ks * 4 + quad) ^ (ca0 & 15)) << 2)];
            bf16x8 a1 = *(const bf16x8*)&smem[ca1 * 64 + (((ks * 4 + quad) ^ (ca1 & 15)) << 2)];
#pragma unroll
            for (int j = 0; j < 8; j++) {
                int cb = ((nf0 + j) * 16 + l15);
                bf16x8 bb = *(const bf16x8*)&smem[cb * 64 + (((ks * 4 + quad) ^ (cb & 15)) << 2)];
                acc[0][j] = MFMA(a0, bb, acc[0][j]);
                acc[1][j] = MFMA(a1, bb, acc[1][j]);
            }
        }
        float* gp = Gf + (size_t)b * 65536;
        for (int fm = 0; fm < 2; fm++)
            for (int j = 0; j < 8; j++)
                for (int r = 0; r < 4; r++) {
                    int row = (mr2 + fm) * 16 + quad * 4 + r;
                    int col = (nf0 + j) * 16 + l15;
                    atomicAdd(gp + row * 256 + col, acc[fm][j][r]);
                }
    }
}

// K2: weight prep + zero G. grid = 1024.
__global__ __launch_bounds__(256) void k_prep(const float* __restrict__ Wqkv,
                                              const float* __restrict__ Wout,
                                              u16* __restrict__ WqkvT, u16* __restrict__ WvTn,
                                              u16* __restrict__ WoutT, float* __restrict__ Gf) {
    int i = blockIdx.x * 256 + threadIdx.x;
    if (i < 512 * 256) { int o = i >> 8, c = i & 255; WqkvT[i] = f2bf(Wqkv[c * 768 + o]); }
    if (i < 256 * 256) {
        int e = i >> 8, o = i & 255;
        WvTn[i] = f2bf(Wqkv[e * 768 + 512 + o]);
        WoutT[i] = f2bf(Wout[o * 256 + e]);
    }
    float4 z4 = {0.f, 0.f, 0.f, 0.f};
    if (i < 262144) ((float4*)Gf)[i] = z4;
}

// K3: G fp32 -> hi/lo bf16 split. grid 1024.
__global__ __launch_bounds__(256) void k_g2b(const float* __restrict__ Gf,
                                             u16* __restrict__ Ghi, u16* __restrict__ Glo) {
    int idx = blockIdx.x * 256 + threadIdx.x;  // < 262144 float4s
    float4 s = ((const float4*)Gf)[idx];
    u16 h0 = f2bf(s.x), h1 = f2bf(s.y), h2 = f2bf(s.z), h3 = f2bf(s.w);
    u16 l0 = f2bf(s.x - bf2f(h0)), l1 = f2bf(s.y - bf2f(h1));
    u16 l2 = f2bf(s.z - bf2f(h2)), l3 = f2bf(s.w - bf2f(h3));
    uint2 ph; ph.x = (unsigned)h0 | ((unsigned)h1 << 16); ph.y = (unsigned)h2 | ((unsigned)h3 << 16);
    uint2 pl; pl.x = (unsigned)l0 | ((unsigned)l1 << 16); pl.y = (unsigned)l2 | ((unsigned)l3 << 16);
    *(uint2*)(Ghi + (size_t)idx * 4) = ph;
    *(uint2*)(Glo + (size_t)idx * 4) = pl;
}

// K4: Sq = Wqk (512x256) . (Ghi + Glo), hi/lo output. grid = 16*8 = 128
__global__ __launch_bounds__(256) void k_sq(const u16* __restrict__ A,
                                            const u16* __restrict__ Ghi, const u16* __restrict__ Glo,
                                            u16* __restrict__ Shi, u16* __restrict__ Slo) {
    __shared__ __align__(16) u16 aT[128 * 32];
    __shared__ __align__(16) u16 bT[128 * 32];
    int bid = blockIdx.x;
    int b = bid >> 3;
    int r2 = bid & 7;
    int mbase = (r2 >> 1) * 128, nbase = (r2 & 1) * 128;
    int t = threadIdx.x, w = t >> 6, lane = t & 63, l15 = lane & 15, quad = lane >> 4;
    int srow = lane >> 2;
    int g8 = (((lane & 3) ^ ((lane >> 3) & 3)) << 3);
    const u16* gA = A + (size_t)(mbase + w * 32 + srow) * 256 + g8;
    const u16* gBh = Ghi + (size_t)b * 65536 + (size_t)(nbase + w * 32 + srow) * 256 + g8;
    const u16* gBl = Glo + (size_t)b * 65536 + (size_t)(nbase + w * 32 + srow) * 256 + g8;
    u16* lA = aT + w * 1024;
    u16* lB = bT + w * 1024;
    int cOff = ((quad ^ ((l15 >> 1) & 3)) << 3);
    f32x4 acc[2][8];
    f32x4 z = {0.f, 0.f, 0.f, 0.f};
    for (int fm = 0; fm < 2; fm++)
        for (int fn = 0; fn < 8; fn++) acc[fm][fn] = z;
    for (int kt = 0; kt < 16; kt++) {
        int kb = (kt & 7) * 32;
        const u16* gB = (kt < 8) ? gBh : gBl;
        if (kt) __syncthreads();
        gload16(gA + kb, lA);
        gload16(gA + 16 * 256 + kb, lA + 512);
        gload16(gB + kb, lB);
        gload16(gB + 16 * 256 + kb, lB + 512);
        __syncthreads();
        bf16x8 af0 = *(const bf16x8*)&aT[(w * 32 + l15) * 32 + cOff];
        bf16x8 af1 = *(const bf16x8*)&aT[(w * 32 + 16 + l15) * 32 + cOff];
        for (int fn = 0; fn < 8; fn++) {
            bf16x8 bfr = *(const bf16x8*)&bT[(fn * 16 + l15) * 32 + cOff];
            acc[0][fn] = MFMA(af0, bfr, acc[0][fn]);
            acc[1][fn] = MFMA(af1, bfr, acc[1][fn]);
        }
    }
    for (int fm = 0; fm < 2; fm++)
        for (int fn = 0; fn < 8; fn++)
            for (int r = 0; r < 4; r++) {
                int row = mbase + w * 32 + fm * 16 + quad * 4 + r;
                int col = nbase + fn * 16 + l15;
                float v = acc[fm][fn][r];
                u16 hi = f2bf(v);
                Shi[((size_t)b * 512 + row) * 256 + col] = hi;
                Slo[((size_t)b * 512 + row) * 256 + col] = f2bf(v - bf2f(hi));
            }
}

// K5: generic 128x128-tile GEMM, K=256 (used for F = M.Wv^T). mode 0: bf16 out.
__global__ __launch_bounds__(256) void k_gemm(const u16* __restrict__ A, size_t aStrB,
                                              const u16* __restrict__ Bb, size_t bStrB,
                                              int mtiles, int ntiles,
                                              u16* __restrict__ o16, float* __restrict__ o32,
                                              const float* __restrict__ bias,
                                              size_t oStrB, int oRstr, int mode) {
    __shared__ __align__(16) u16 aT[128 * 32];
    __shared__ __align__(16) u16 bT[128 * 32];
    int bid = blockIdx.x;
    int per_b = mtiles * ntiles;
    int b = bid / per_b;
    int r2 = bid % per_b;
    int mbase = (r2 / ntiles) * 128, nbase = (r2 % ntiles) * 128;
    int t = threadIdx.x, w = t >> 6, lane = t & 63, l15 = lane & 15, quad = lane >> 4;
    const u16* Ap = A + (size_t)b * aStrB;
    const u16* Bp = Bb + (size_t)b * bStrB;
    int srow = lane >> 2;
    int g8 = (((lane & 3) ^ ((lane >> 3) & 3)) << 3);
    const u16* gA = Ap + (size_t)(mbase + w * 32 + srow) * 256 + g8;
    const u16* gB = Bp + (size_t)(nbase + w * 32 + srow) * 256 + g8;
    u16* lA = aT + w * 1024;
    u16* lB = bT + w * 1024;
    int cOff = ((quad ^ ((l15 >> 1) & 3)) << 3);
    f32x4 acc[2][8];
    f32x4 z = {0.f, 0.f, 0.f, 0.f};
    for (int fm = 0; fm < 2; fm++)
        for (int fn = 0; fn < 8; fn++) acc[fm][fn] = z;
    for (int kt = 0; kt < 8; kt++) {
        int kb = kt * 32;
        if (kt) __syncthreads();
        gload16(gA + kb, lA);
        gload16(gA + 16 * 256 + kb, lA + 512);
        gload16(gB + kb, lB);
        gload16(gB + 16 * 256 + kb, lB + 512);
        __syncthreads();
        bf16x8 af0 = *(const bf16x8*)&aT[(w * 32 + l15) * 32 + cOff];
        bf16x8 af1 = *(const bf16x8*)&aT[(w * 32 + 16 + l15) * 32 + cOff];
        for (int fn = 0; fn < 8; fn++) {
            bf16x8 bfr = *(const bf16x8*)&bT[(fn * 16 + l15) * 32 + cOff];
            acc[0][fn] = MFMA(af0, bfr, acc[0][fn]);
            acc[1][fn] = MFMA(af1, bfr, acc[1][fn]);
        }
    }
    if (mode == 0) {
        for (int fm = 0; fm < 2; fm++)
            for (int fn = 0; fn < 8; fn++)
                for (int r = 0; r < 4; r++) {
                    int row = mbase + w * 32 + fm * 16 + quad * 4 + r;
                    int col = nbase + fn * 16 + l15;
                    o16[(size_t)b * oStrB + (size_t)row * oRstr + col] = f2bf(acc[fm][fn][r]);
                }
    } else {
        for (int fm = 0; fm < 2; fm++)
            for (int fn = 0; fn < 8; fn++)
                for (int r = 0; r < 4; r++) {
                    int row = mbase + w * 32 + fm * 16 + quad * 4 + r;
                    int col = nbase + fn * 16 + l15;
                    o32[(size_t)b * oStrB + (size_t)row * oRstr + col] = acc[fm][fn][r] + bias[row];
                }
    }
}

// K6: out = F (256x256) . X^T + bias, BM=256 (single m-tile -> B read once).
// grid = 16 b * 32 ntiles = 512. acc[4][8] per wave (64-row band).
__global__ __launch_bounds__(256) void k_out(const u16* __restrict__ F, const u16* __restrict__ xlnT,
                                             const float* __restrict__ bias, float* __restrict__ out) {
    __shared__ __align__(16) u16 aT[256 * 32];
    __shared__ __align__(16) u16 bT[128 * 32];
    int bid = blockIdx.x;
    int b = bid >> 5, nt = bid & 31;
    int nbase = nt * 128;
    int t = threadIdx.x, w = t >> 6, lane = t & 63, l15 = lane & 15, quad = lane >> 4;
    int srow = lane >> 2;
    int g8 = (((lane & 3) ^ ((lane >> 3) & 3)) << 3);
    const u16* gA = F + (size_t)b * 65536 + (size_t)(w * 64 + srow) * 256 + g8;
    const u16* gB = xlnT + (size_t)b * 4096 * 256 + (size_t)(nbase + w * 32 + srow) * 256 + g8;
    u16* lA = aT + w * 2048;
    u16* lB = bT + w * 1024;
    int cOff = ((quad ^ ((l15 >> 1) & 3)) << 3);
    f32x4 acc[4][8];
    f32x4 z = {0.f, 0.f, 0.f, 0.f};
    for (int fm = 0; fm < 4; fm++)
        for (int fn = 0; fn < 8; fn++) acc[fm][fn] = z;
    for (int kt = 0; kt < 8; kt++) {
        int kb = kt * 32;
        if (kt) __syncthreads();
        gload16(gA + kb, lA);
        gload16(gA + 16 * 256 + kb, lA + 512);
        gload16(gA + 32 * 256 + kb, lA + 1024);
        gload16(gA + 48 * 256 + kb, lA + 1536);
        gload16(gB + kb, lB);
        gload16(gB + 16 * 256 + kb, lB + 512);
        __syncthreads();
        bf16x8 af[4];
#pragma unroll
        for (int fm = 0; fm < 4; fm++)
            af[fm] = *(const bf16x8*)&aT[(w * 64 + fm * 16 + l15) * 32 + cOff];
        for (int fn = 0; fn < 8; fn++) {
            bf16x8 bfr = *(const bf16x8*)&bT[(fn * 16 + l15) * 32 + cOff];
#pragma unroll
            for (int fm = 0; fm < 4; fm++) acc[fm][fn] = MFMA(af[fm], bfr, acc[fm][fn]);
        }
    }
    for (int fm = 0; fm < 4; fm++)
        for (int fn = 0; fn < 8; fn++)
            for (int r = 0; r < 4; r++) {
                int row = w * 64 + fm * 16 + quad * 4 + r;
                int col = nbase + fn * 16 + l15;
                out[((size_t)b * 256 + row) * 4096 + col] = acc[fm][fn][r] + bias[row];
            }
}

// K7: per (b,h): sim = (Sq_hi+Sq_lo) . Wk^T, norms from diag, softmax, M_h = wo.attn
__global__ __launch_bounds__(256) void k_attn(const u16* __restrict__ Shi,
                                              const u16* __restrict__ Slo,
                                              const u16* __restrict__ WqkvT,
                                              const u16* __restrict__ WoutT,
                                              const float* __restrict__ temp,
                                              u16* __restrict__ M_all) {
    int bh = blockIdx.x;
    int b = bh >> 3, h = bh & 7;
    __shared__ u16 sqh[32 * 264], sql[32 * 264], skh[32 * 264], wq[32 * 264], wk[32 * 264];
    __shared__ u16 wo[256 * 40];
    __shared__ u16 attnT[32 * 40];
    __shared__ float simS[32 * 33];
    __shared__ float redn[4 * 64];
    __shared__ float scq[32], sck[32];
    int t = threadIdx.x, w = t >> 6, lane = t & 63, l15 = lane & 15, quad = lane >> 4;
    {
        int r = t >> 3, cc0 = (t & 7) * 32;
        const u16* gqh = Shi + ((size_t)(b * 512) + h * 32 + r) * 256 + cc0;
        const u16* gql = Slo + ((size_t)(b * 512) + h * 32 + r) * 256 + cc0;
        const u16* gkh = Shi + ((size_t)(b * 512) + 256 + h * 32 + r) * 256 + cc0;
        const u16* gwq = WqkvT + (size_t)(h * 32 + r) * 256 + cc0;
        const u16* gwk = WqkvT + (size_t)(256 + h * 32 + r) * 256 + cc0;
#pragma unroll
        for (int k = 0; k < 4; k++) {
            *(uint4*)&sqh[r * 264 + cc0 + k * 8] = *(const uint4*)(gqh + k * 8);
            *(uint4*)&sql[r * 264 + cc0 + k * 8] = *(const uint4*)(gql + k * 8);
            *(uint4*)&skh[r * 264 + cc0 + k * 8] = *(const uint4*)(gkh + k * 8);
            *(uint4*)&wq[r * 264 + cc0 + k * 8] = *(const uint4*)(gwq + k * 8);
            *(uint4*)&wk[r * 264 + cc0 + k * 8] = *(const uint4*)(gwk + k * 8);
        }
        const u16* gwo = WoutT + (size_t)t * 256 + h * 32;
#pragma unroll
        for (int k = 0; k < 4; k++) *(uint4*)&wo[t * 40 + k * 8] = *(const uint4*)(gwo + k * 8);
    }
    __syncthreads();
    {
        int rn = t & 63, cc = t >> 6;
        int e0 = cc * 64;
        float s = 0.f;
        if (rn < 32) {
            const u16* ph = &sqh[rn * 264];
            const u16* pl = &sql[rn * 264];
            const u16* pb = &wq[rn * 264];
            for (int e = 0; e < 64; e++)
                s += (bf2f(ph[e0 + e]) + bf2f(pl[e0 + e])) * bf2f(pb[e0 + e]);
        } else {
            const u16* ph = &skh[(rn - 32) * 264];
            const u16* pb = &wk[(rn - 32) * 264];
            for (int e = 0; e < 64; e++)
                s += bf2f(ph[e0 + e]) * bf2f(pb[e0 + e]);
        }
        redn[cc * 64 + rn] = s;
    }
    {
        int iq = w >> 1, jq = w & 1;
        f32x4 acc = {0.f, 0.f, 0.f, 0.f};
        for (int s8 = 0; s8 < 8; s8++) {
            bf16x8 a = *(const bf16x8*)&sqh[(iq * 16 + l15) * 264 + s8 * 32 + quad * 8];
            bf16x8 bb = *(const bf16x8*)&wk[(jq * 16 + l15) * 264 + s8 * 32 + quad * 8];
            acc = MFMA(a, bb, acc);
        }
        for (int s8 = 0; s8 < 8; s8++) {
            bf16x8 a = *(const bf16x8*)&sql[(iq * 16 + l15) * 264 + s8 * 32 + quad * 8];
            bf16x8 bb = *(const bf16x8*)&wk[(jq * 16 + l15) * 264 + s8 * 32 + quad * 8];
            acc = MFMA(a, bb, acc);
        }
        for (int r = 0; r < 4; r++)
            simS[(iq * 16 + quad * 4 + r) * 33 + jq * 16 + l15] = acc[r];
    }
    __syncthreads();
    if (t < 32)
        scq[t] = expf(temp[h]) * 8.0f /
                 fmaxf(sqrtf(redn[t] + redn[64 + t] + redn[128 + t] + redn[192 + t]), 1e-12f);
    else if (t < 64) {
        int d = t - 32;
        sck[d] = 1.0f / fmaxf(sqrtf(redn[32 + d] + redn[96 + d] + redn[160 + d] + redn[224 + d]), 1e-12f);
    }
    __syncthreads();
    if (t < 32) {
        float row[32];
        float m = -1e30f, sqv = scq[t];
#pragma unroll
        for (int j = 0; j < 32; j++) {
            float v = simS[t * 33 + j] * sqv * sck[j];
            row[j] = v; m = fmaxf(m, v);
        }
        float s = 0.f;
#pragma unroll
        for (int j = 0; j < 32; j++) { float p = expf(row[j] - m); row[j] = p; s += p; }
        float inv = 1.f / s;
#pragma unroll
        for (int j = 0; j < 32; j++) attnT[j * 40 + t] = f2bf(row[j] * inv);
    }
    __syncthreads();
    {
        f32x4 z = {0.f, 0.f, 0.f, 0.f};
        for (int mf = 0; mf < 4; mf++) {
            bf16x8 a = *(const bf16x8*)&wo[((w * 4 + mf) * 16 + l15) * 40 + quad * 8];
            for (int nf = 0; nf < 2; nf++) {
                bf16x8 bb = *(const bf16x8*)&attnT[(nf * 16 + l15) * 40 + quad * 8];
                f32x4 d = MFMA(a, bb, z);
                for (int r = 0; r < 4; r++) {
                    int c = (w * 4 + mf) * 16 + quad * 4 + r;
                    M_all[((size_t)(b * 256) + c) * 256 + h * 32 + nf * 16 + l15] = f2bf(d[r]);
                }
            }
        }
    }
}

extern "C" void kernel_launch(void* const* d_in, const int* in_sizes, int n_in,
                              void* d_out, int out_size, void* d_ws, size_t ws_size,
                              hipStream_t stream) {
    const float* x     = (const float*)d_in[0];
    const float* gamma = (const float*)d_in[1];
    const float* beta  = (const float*)d_in[2];
    const float* Wqkv  = (const float*)d_in[3];
    const float* temp  = (const float*)d_in[4];
    const float* Wout  = (const float*)d_in[5];
    const float* bout  = (const float*)d_in[6];
    float* out = (float*)d_out;

    char* ws = (char*)d_ws;
    size_t off = 0;
    auto alloc = [&](size_t nbytes) -> void* {
        void* p = ws + off;
        off = (off + nbytes + 255) & ~(size_t)255;
        return p;
    };
    u16* xlnT   = (u16*)alloc((size_t)16 * 4096 * 256 * 2);   // 32 MB (b,n,c)
    u16* WqkvT  = (u16*)alloc((size_t)512 * 256 * 2);
    u16* WvTn   = (u16*)alloc((size_t)256 * 256 * 2);
    u16* WoutT  = (u16*)alloc((size_t)256 * 256 * 2);
    float* Gf   = (float*)alloc((size_t)16 * 65536 * 4);      // 4 MB fp32 Gram
    u16* Gbh    = (u16*)alloc((size_t)16 * 65536 * 2);        // 2 MB
    u16* Gbl    = (u16*)alloc((size_t)16 * 65536 * 2);        // 2 MB
    u16* Sqh    = (u16*)alloc((size_t)16 * 512 * 256 * 2);    // 4 MB
    u16* Sql    = (u16*)alloc((size_t)16 * 512 * 256 * 2);    // 4 MB
    u16* M_all  = (u16*)alloc((size_t)16 * 256 * 256 * 2);    // 2 MB
    u16* F      = (u16*)alloc((size_t)16 * 256 * 256 * 2);    // 2 MB
    (void)ws_size; (void)in_sizes; (void)n_in; (void)out_size;

    hipLaunchKernelGGL(k_prep, dim3(1024), dim3(256), 0, stream, Wqkv, Wout, WqkvT, WvTn, WoutT, Gf);
    hipLaunchKernelGGL(k_lngram, dim3(512), dim3(1024), 0, stream, x, gamma, beta, xlnT, Gf);
    hipLaunchKernelGGL(k_g2b, dim3(1024), dim3(256), 0, stream, Gf, Gbh, Gbl);
    hipLaunchKernelGGL(k_sq, dim3(128), dim3(256), 0, stream, WqkvT, Gbh, Gbl, Sqh, Sql);
    hipLaunchKernelGGL(k_attn, dim3(128), dim3(256), 0, stream, Sqh, Sql, WqkvT, WoutT, temp, M_all);
    // F[b] = M_b (256x256) . Wv^T  (B-rows = WvTn rows)
    hipLaunchKernelGGL(k_gemm, dim3(64), dim3(256), 0, stream,
                       M_all, (size_t)65536, WvTn, (size_t)0, 2, 2,
                       F, (float*)nullptr, (const float*)nullptr,
                       (size_t)65536, 256, 0);
    // out[b] = F_b . X_b (+bias), BM=256
    hipLaunchKernelGGL(k_out, dim3(512), dim3(256), 0, stream, F, xlnT, bout, out);
}

// Round 6
// 255.464 us; speedup vs baseline: 1.0803x; 1.0803x over previous
//
#include <hip/hip_runtime.h>

typedef unsigned short u16;
typedef __bf16 bf16x8 __attribute__((ext_vector_type(8)));
typedef float f32x4 __attribute__((ext_vector_type(4)));

#define MFMA(a, b, c) __builtin_amdgcn_mfma_f32_16x16x32_bf16((a), (b), (c), 0, 0, 0)

__device__ __forceinline__ u16 f2bf(float f) {
    unsigned u = __float_as_uint(f);
    unsigned r = (u + 0x7fffu + ((u >> 16) & 1u)) >> 16;  // RNE
    return (u16)r;
}
__device__ __forceinline__ float bf2f(u16 h) { return __uint_as_float(((unsigned)h) << 16); }

typedef unsigned int u32_g __attribute__((address_space(1)));
typedef unsigned int u32_l __attribute__((address_space(3)));
__device__ __forceinline__ void gload16(const void* g, void* l) {
    __builtin_amdgcn_global_load_lds((const u32_g*)g, (u32_l*)l, 16, 0, 0);
}

// ---------------------------------------------------------------------------
// Shapes: b=16, c=256, n=4096, heads=8, dim_head=32
// Gram-trick pipeline, LN+Gram fused; block-private fp32 partials (NO atomics).
// ---------------------------------------------------------------------------

// K1: fused LayerNorm + Gram partial. grid = 16 b * 16 chunks = 256, block = 1024.
// Each block: 256 n, processed as TWO 128-n sub-chunks; Gram acc[2][8] persists
// in registers across sub-chunks; one 256x256 fp32 partial written at the end.
// Thread (np = t&63 -> n pair within sub-chunk, cg = t>>6 = wave -> 16 c rows).
// LDS 64 KB time-shared: [stats] then [xst bf16 tile], per sub-chunk.
// xst swizzle (HW-verified r5): pair np of row c at dword
//   c*64 + ((((np>>2) ^ (c&15)) << 2) | (np&3));  frag read slot ks*4+quad.
__global__ __launch_bounds__(1024) void k_lngram(const float* __restrict__ x,
                                                 const float* __restrict__ gamma,
                                                 const float* __restrict__ beta,
                                                 u16* __restrict__ xlnT, float* __restrict__ Gp) {
    __shared__ __align__(16) unsigned smem[256 * 64];  // 64 KB
    float* sf = (float*)smem;
    int bid = blockIdx.x;
    int b = bid >> 4, ch = bid & 15;
    int t = threadIdx.x;
    int np = t & 63, cg = t >> 6;
    int lane = t & 63, l15 = lane & 15, quad = lane >> 4;
    int w = t >> 6;
    int mr2 = (w & 7) * 2, nf0 = (w >> 3) * 8;
    f32x4 acc[2][8];
    {
        f32x4 z = {0.f, 0.f, 0.f, 0.f};
        for (int fm = 0; fm < 2; fm++)
            for (int j = 0; j < 8; j++) acc[fm][j] = z;
    }
    for (int sc = 0; sc < 2; sc++) {
        int nb = ch * 256 + sc * 128;
        // P1: load 16 c-rows x 2 n, partial stats
        const float* xp = x + ((size_t)(b * 256 + cg * 16)) * 4096 + nb + np * 2;
        float2 v[16];
        float s0 = 0.f, s1 = 0.f, s20 = 0.f, s21 = 0.f;
#pragma unroll
        for (int i = 0; i < 16; i++) {
            float2 f = *(const float2*)(xp + (size_t)i * 4096);
            v[i] = f;
            s0 += f.x; s20 += f.x * f.x;
            s1 += f.y; s21 += f.y * f.y;
        }
        if (sc) __syncthreads();  // previous MFMA reads done before stats overwrite
        sf[cg * 128 + 2 * np] = s0;
        sf[cg * 128 + 2 * np + 1] = s1;
        sf[2048 + cg * 128 + 2 * np] = s20;
        sf[2048 + cg * 128 + 2 * np + 1] = s21;
        __syncthreads();
        // P2: finalize stats for 128 n
        if (t < 128) {
            float s = 0.f, s2 = 0.f;
#pragma unroll
            for (int g = 0; g < 16; g++) { s += sf[g * 128 + t]; s2 += sf[2048 + g * 128 + t]; }
            float m = s * (1.f / 256.f);
            float var = s2 * (1.f / 256.f) - m * m;
            sf[4096 + t] = m;
            sf[4224 + t] = rsqrtf(var + 1e-5f);
        }
        __syncthreads();
        float m0 = sf[4096 + 2 * np], r0 = sf[4224 + 2 * np];
        float m1 = sf[4096 + 2 * np + 1], r1 = sf[4224 + 2 * np + 1];
        __syncthreads();  // all mu/rs reads done before xst overwrites smem
        // P3: normalize in regs, write xst (swizzled) + xlnT global
        u16 hA[16], hB[16];
#pragma unroll
        for (int i = 0; i < 16; i++) {
            int c = cg * 16 + i;
            float g = gamma[c], e = beta[c];
            float a = (v[i].x - m0) * r0 * g + e;
            float bv = (v[i].y - m1) * r1 * g + e;
            u16 ha = f2bf(a), hb = f2bf(bv);
            hA[i] = ha; hB[i] = hb;
            int dw = c * 64 + ((((np >> 2) ^ (c & 15)) << 2) | (np & 3));
            smem[dw] = (unsigned)ha | ((unsigned)hb << 16);
        }
        {
            u16* dst0 = xlnT + ((size_t)(b * 4096 + nb + 2 * np)) * 256 + cg * 16;
            uint4 qa, qb;
            qa.x = (unsigned)hA[0] | ((unsigned)hA[1] << 16);
            qa.y = (unsigned)hA[2] | ((unsigned)hA[3] << 16);
            qa.z = (unsigned)hA[4] | ((unsigned)hA[5] << 16);
            qa.w = (unsigned)hA[6] | ((unsigned)hA[7] << 16);
            qb.x = (unsigned)hA[8] | ((unsigned)hA[9] << 16);
            qb.y = (unsigned)hA[10] | ((unsigned)hA[11] << 16);
            qb.z = (unsigned)hA[12] | ((unsigned)hA[13] << 16);
            qb.w = (unsigned)hA[14] | ((unsigned)hA[15] << 16);
            *(uint4*)dst0 = qa;
            *(uint4*)(dst0 + 8) = qb;
            u16* dst1 = dst0 + 256;
            qa.x = (unsigned)hB[0] | ((unsigned)hB[1] << 16);
            qa.y = (unsigned)hB[2] | ((unsigned)hB[3] << 16);
            qa.z = (unsigned)hB[4] | ((unsigned)hB[5] << 16);
            qa.w = (unsigned)hB[6] | ((unsigned)hB[7] << 16);
            qb.x = (unsigned)hB[8] | ((unsigned)hB[9] << 16);
            qb.y = (unsigned)hB[10] | ((unsigned)hB[11] << 16);
            qb.z = (unsigned)hB[12] | ((unsigned)hB[13] << 16);
            qb.w = (unsigned)hB[14] | ((unsigned)hB[15] << 16);
            *(uint4*)dst1 = qa;
            *(uint4*)(dst1 + 8) = qb;
        }
        __syncthreads();
        // P4: Gram MFMA, accumulate into persistent acc
#pragma unroll
        for (int ks = 0; ks < 4; ks++) {
            int ca0 = (mr2 * 16 + l15);
            int ca1 = ((mr2 + 1) * 16 + l15);
            bf16x8 a0 = *(const bf16x8*)&smem[ca0 * 64 + (((ks * 4 + quad) ^ (ca0 & 15)) << 2)];
            bf16x8 a1 = *(const bf16x8*)&smem[ca1 * 64 + (((ks * 4 + quad) ^ (ca1 & 15)) << 2)];
#pragma unroll
            for (int j = 0; j < 8; j++) {
                int cb = ((nf0 + j) * 16 + l15);
                bf16x8 bb = *(const bf16x8*)&smem[cb * 64 + (((ks * 4 + quad) ^ (cb & 15)) << 2)];
                acc[0][j] = MFMA(a0, bb, acc[0][j]);
                acc[1][j] = MFMA(a1, bb, acc[1][j]);
            }
        }
    }
    // write block-private partial (non-atomic)
    float* gp = Gp + (size_t)(b * 16 + ch) * 65536;
    for (int fm = 0; fm < 2; fm++)
        for (int j = 0; j < 8; j++)
            for (int r = 0; r < 4; r++) {
                int row = (mr2 + fm) * 16 + quad * 4 + r;
                int col = (nf0 + j) * 16 + l15;
                gp[row * 256 + col] = acc[fm][j][r];
            }
}

// K2: weight prep. grid = 1024.
__global__ __launch_bounds__(256) void k_prep(const float* __restrict__ Wqkv,
                                              const float* __restrict__ Wout,
                                              u16* __restrict__ WqkvT, u16* __restrict__ WvTn,
                                              u16* __restrict__ WoutT) {
    int i = blockIdx.x * 256 + threadIdx.x;
    if (i < 512 * 256) { int o = i >> 8, c = i & 255; WqkvT[i] = f2bf(Wqkv[c * 768 + o]); }
    if (i < 256 * 256) {
        int e = i >> 8, o = i & 255;
        WvTn[i] = f2bf(Wqkv[e * 768 + 512 + o]);
        WoutT[i] = f2bf(Wout[o * 256 + e]);
    }
}

// K3: G = sum of 16 partials -> hi/lo bf16 split. grid 1024 x 256.
__global__ __launch_bounds__(256) void k_g2b(const float* __restrict__ Gp,
                                             u16* __restrict__ Ghi, u16* __restrict__ Glo) {
    int g = blockIdx.x * 256 + threadIdx.x;  // < 262144; b = g>>14, e = g&16383
    int b = g >> 14, e = g & 16383;
    const float4* p = (const float4*)Gp + (size_t)(b * 16) * 16384 + e;
    float4 s = p[0];
#pragma unroll
    for (int j = 1; j < 16; j++) {
        float4 v = p[(size_t)j * 16384];
        s.x += v.x; s.y += v.y; s.z += v.z; s.w += v.w;
    }
    u16 h0 = f2bf(s.x), h1 = f2bf(s.y), h2 = f2bf(s.z), h3 = f2bf(s.w);
    u16 l0 = f2bf(s.x - bf2f(h0)), l1 = f2bf(s.y - bf2f(h1));
    u16 l2 = f2bf(s.z - bf2f(h2)), l3 = f2bf(s.w - bf2f(h3));
    uint2 ph; ph.x = (unsigned)h0 | ((unsigned)h1 << 16); ph.y = (unsigned)h2 | ((unsigned)h3 << 16);
    uint2 pl; pl.x = (unsigned)l0 | ((unsigned)l1 << 16); pl.y = (unsigned)l2 | ((unsigned)l3 << 16);
    *(uint2*)(Ghi + (size_t)g * 4) = ph;
    *(uint2*)(Glo + (size_t)g * 4) = pl;
}

// K4: Sq = Wqk (512x256) . (Ghi + Glo), hi/lo output. grid = 16*8 = 128
__global__ __launch_bounds__(256) void k_sq(const u16* __restrict__ A,
                                            const u16* __restrict__ Ghi, const u16* __restrict__ Glo,
                                            u16* __restrict__ Shi, u16* __restrict__ Slo) {
    __shared__ __align__(16) u16 aT[128 * 32];
    __shared__ __align__(16) u16 bT[128 * 32];
    int bid = blockIdx.x;
    int b = bid >> 3;
    int r2 = bid & 7;
    int mbase = (r2 >> 1) * 128, nbase = (r2 & 1) * 128;
    int t = threadIdx.x, w = t >> 6, lane = t & 63, l15 = lane & 15, quad = lane >> 4;
    int srow = lane >> 2;
    int g8 = (((lane & 3) ^ ((lane >> 3) & 3)) << 3);
    const u16* gA = A + (size_t)(mbase + w * 32 + srow) * 256 + g8;
    const u16* gBh = Ghi + (size_t)b * 65536 + (size_t)(nbase + w * 32 + srow) * 256 + g8;
    const u16* gBl = Glo + (size_t)b * 65536 + (size_t)(nbase + w * 32 + srow) * 256 + g8;
    u16* lA = aT + w * 1024;
    u16* lB = bT + w * 1024;
    int cOff = ((quad ^ ((l15 >> 1) & 3)) << 3);
    f32x4 acc[2][8];
    f32x4 z = {0.f, 0.f, 0.f, 0.f};
    for (int fm = 0; fm < 2; fm++)
        for (int fn = 0; fn < 8; fn++) acc[fm][fn] = z;
    for (int kt = 0; kt < 16; kt++) {
        int kb = (kt & 7) * 32;
        const u16* gB = (kt < 8) ? gBh : gBl;
        if (kt) __syncthreads();
        gload16(gA + kb, lA);
        gload16(gA + 16 * 256 + kb, lA + 512);
        gload16(gB + kb, lB);
        gload16(gB + 16 * 256 + kb, lB + 512);
        __syncthreads();
        bf16x8 af0 = *(const bf16x8*)&aT[(w * 32 + l15) * 32 + cOff];
        bf16x8 af1 = *(const bf16x8*)&aT[(w * 32 + 16 + l15) * 32 + cOff];
        for (int fn = 0; fn < 8; fn++) {
            bf16x8 bfr = *(const bf16x8*)&bT[(fn * 16 + l15) * 32 + cOff];
            acc[0][fn] = MFMA(af0, bfr, acc[0][fn]);
            acc[1][fn] = MFMA(af1, bfr, acc[1][fn]);
        }
    }
    for (int fm = 0; fm < 2; fm++)
        for (int fn = 0; fn < 8; fn++)
            for (int r = 0; r < 4; r++) {
                int row = mbase + w * 32 + fm * 16 + quad * 4 + r;
                int col = nbase + fn * 16 + l15;
                float v = acc[fm][fn][r];
                u16 hi = f2bf(v);
                Shi[((size_t)b * 512 + row) * 256 + col] = hi;
                Slo[((size_t)b * 512 + row) * 256 + col] = f2bf(v - bf2f(hi));
            }
}

// K5: generic 128x128-tile GEMM, K=256 (used for F = M.Wv^T). mode 0: bf16 out.
__global__ __launch_bounds__(256) void k_gemm(const u16* __restrict__ A, size_t aStrB,
                                              const u16* __restrict__ Bb, size_t bStrB,
                                              int mtiles, int ntiles,
                                              u16* __restrict__ o16, float* __restrict__ o32,
                                              const float* __restrict__ bias,
                                              size_t oStrB, int oRstr, int mode) {
    __shared__ __align__(16) u16 aT[128 * 32];
    __shared__ __align__(16) u16 bT[128 * 32];
    int bid = blockIdx.x;
    int per_b = mtiles * ntiles;
    int b = bid / per_b;
    int r2 = bid % per_b;
    int mbase = (r2 / ntiles) * 128, nbase = (r2 % ntiles) * 128;
    int t = threadIdx.x, w = t >> 6, lane = t & 63, l15 = lane & 15, quad = lane >> 4;
    const u16* Ap = A + (size_t)b * aStrB;
    const u16* Bp = Bb + (size_t)b * bStrB;
    int srow = lane >> 2;
    int g8 = (((lane & 3) ^ ((lane >> 3) & 3)) << 3);
    const u16* gA = Ap + (size_t)(mbase + w * 32 + srow) * 256 + g8;
    const u16* gB = Bp + (size_t)(nbase + w * 32 + srow) * 256 + g8;
    u16* lA = aT + w * 1024;
    u16* lB = bT + w * 1024;
    int cOff = ((quad ^ ((l15 >> 1) & 3)) << 3);
    f32x4 acc[2][8];
    f32x4 z = {0.f, 0.f, 0.f, 0.f};
    for (int fm = 0; fm < 2; fm++)
        for (int fn = 0; fn < 8; fn++) acc[fm][fn] = z;
    for (int kt = 0; kt < 8; kt++) {
        int kb = kt * 32;
        if (kt) __syncthreads();
        gload16(gA + kb, lA);
        gload16(gA + 16 * 256 + kb, lA + 512);
        gload16(gB + kb, lB);
        gload16(gB + 16 * 256 + kb, lB + 512);
        __syncthreads();
        bf16x8 af0 = *(const bf16x8*)&aT[(w * 32 + l15) * 32 + cOff];
        bf16x8 af1 = *(const bf16x8*)&aT[(w * 32 + 16 + l15) * 32 + cOff];
        for (int fn = 0; fn < 8; fn++) {
            bf16x8 bfr = *(const bf16x8*)&bT[(fn * 16 + l15) * 32 + cOff];
            acc[0][fn] = MFMA(af0, bfr, acc[0][fn]);
            acc[1][fn] = MFMA(af1, bfr, acc[1][fn]);
        }
    }
    if (mode == 0) {
        for (int fm = 0; fm < 2; fm++)
            for (int fn = 0; fn < 8; fn++)
                for (int r = 0; r < 4; r++) {
                    int row = mbase + w * 32 + fm * 16 + quad * 4 + r;
                    int col = nbase + fn * 16 + l15;
                    o16[(size_t)b * oStrB + (size_t)row * oRstr + col] = f2bf(acc[fm][fn][r]);
                }
    } else {
        for (int fm = 0; fm < 2; fm++)
            for (int fn = 0; fn < 8; fn++)
                for (int r = 0; r < 4; r++) {
                    int row = mbase + w * 32 + fm * 16 + quad * 4 + r;
                    int col = nbase + fn * 16 + l15;
                    o32[(size_t)b * oStrB + (size_t)row * oRstr + col] = acc[fm][fn][r] + bias[row];
                }
    }
}

// K6: out = F (256x256) . X^T + bias, BM=256. grid = 512.
__global__ __launch_bounds__(256) void k_out(const u16* __restrict__ F, const u16* __restrict__ xlnT,
                                             const float* __restrict__ bias, float* __restrict__ out) {
    __shared__ __align__(16) u16 aT[256 * 32];
    __shared__ __align__(16) u16 bT[128 * 32];
    int bid = blockIdx.x;
    int b = bid >> 5, nt = bid & 31;
    int nbase = nt * 128;
    int t = threadIdx.x, w = t >> 6, lane = t & 63, l15 = lane & 15, quad = lane >> 4;
    int srow = lane >> 2;
    int g8 = (((lane & 3) ^ ((lane >> 3) & 3)) << 3);
    const u16* gA = F + (size_t)b * 65536 + (size_t)(w * 64 + srow) * 256 + g8;
    const u16* gB = xlnT + (size_t)b * 4096 * 256 + (size_t)(nbase + w * 32 + srow) * 256 + g8;
    u16* lA = aT + w * 2048;
    u16* lB = bT + w * 1024;
    int cOff = ((quad ^ ((l15 >> 1) & 3)) << 3);
    f32x4 acc[4][8];
    f32x4 z = {0.f, 0.f, 0.f, 0.f};
    for (int fm = 0; fm < 4; fm++)
        for (int fn = 0; fn < 8; fn++) acc[fm][fn] = z;
    for (int kt = 0; kt < 8; kt++) {
        int kb = kt * 32;
        if (kt) __syncthreads();
        gload16(gA + kb, lA);
        gload16(gA + 16 * 256 + kb, lA + 512);
        gload16(gA + 32 * 256 + kb, lA + 1024);
        gload16(gA + 48 * 256 + kb, lA + 1536);
        gload16(gB + kb, lB);
        gload16(gB + 16 * 256 + kb, lB + 512);
        __syncthreads();
        bf16x8 af[4];
#pragma unroll
        for (int fm = 0; fm < 4; fm++)
            af[fm] = *(const bf16x8*)&aT[(w * 64 + fm * 16 + l15) * 32 + cOff];
        for (int fn = 0; fn < 8; fn++) {
            bf16x8 bfr = *(const bf16x8*)&bT[(fn * 16 + l15) * 32 + cOff];
#pragma unroll
            for (int fm = 0; fm < 4; fm++) acc[fm][fn] = MFMA(af[fm], bfr, acc[fm][fn]);
        }
    }
    for (int fm = 0; fm < 4; fm++)
        for (int fn = 0; fn < 8; fn++)
            for (int r = 0; r < 4; r++) {
                int row = w * 64 + fm * 16 + quad * 4 + r;
                int col = nbase + fn * 16 + l15;
                out[((size_t)b * 256 + row) * 4096 + col] = acc[fm][fn][r] + bias[row];
            }
}

// K7: per (b,h): sim = (Sq_hi+Sq_lo) . Wk^T, norms from diag, softmax, M_h = wo.attn
__global__ __launch_bounds__(256) void k_attn(const u16* __restrict__ Shi,
                                              const u16* __restrict__ Slo,
                                              const u16* __restrict__ WqkvT,
                                              const u16* __restrict__ WoutT,
                                              const float* __restrict__ temp,
                                              u16* __restrict__ M_all) {
    int bh = blockIdx.x;
    int b = bh >> 3, h = bh & 7;
    __shared__ u16 sqh[32 * 264], sql[32 * 264], skh[32 * 264], wq[32 * 264], wk[32 * 264];
    __shared__ u16 wo[256 * 40];
    __shared__ u16 attnT[32 * 40];
    __shared__ float simS[32 * 33];
    __shared__ float redn[4 * 64];
    __shared__ float scq[32], sck[32];
    int t = threadIdx.x, w = t >> 6, lane = t & 63, l15 = lane & 15, quad = lane >> 4;
    {
        int r = t >> 3, cc0 = (t & 7) * 32;
        const u16* gqh = Shi + ((size_t)(b * 512) + h * 32 + r) * 256 + cc0;
        const u16* gql = Slo + ((size_t)(b * 512) + h * 32 + r) * 256 + cc0;
        const u16* gkh = Shi + ((size_t)(b * 512) + 256 + h * 32 + r) * 256 + cc0;
        const u16* gwq = WqkvT + (size_t)(h * 32 + r) * 256 + cc0;
        const u16* gwk = WqkvT + (size_t)(256 + h * 32 + r) * 256 + cc0;
#pragma unroll
        for (int k = 0; k < 4; k++) {
            *(uint4*)&sqh[r * 264 + cc0 + k * 8] = *(const uint4*)(gqh + k * 8);
            *(uint4*)&sql[r * 264 + cc0 + k * 8] = *(const uint4*)(gql + k * 8);
            *(uint4*)&skh[r * 264 + cc0 + k * 8] = *(const uint4*)(gkh + k * 8);
            *(uint4*)&wq[r * 264 + cc0 + k * 8] = *(const uint4*)(gwq + k * 8);
            *(uint4*)&wk[r * 264 + cc0 + k * 8] = *(const uint4*)(gwk + k * 8);
        }
        const u16* gwo = WoutT + (size_t)t * 256 + h * 32;
#pragma unroll
        for (int k = 0; k < 4; k++) *(uint4*)&wo[t * 40 + k * 8] = *(const uint4*)(gwo + k * 8);
    }
    __syncthreads();
    {
        int rn = t & 63, cc = t >> 6;
        int e0 = cc * 64;
        float s = 0.f;
        if (rn < 32) {
            const u16* ph = &sqh[rn * 264];
            const u16* pl = &sql[rn * 264];
            const u16* pb = &wq[rn * 264];
            for (int e = 0; e < 64; e++)
                s += (bf2f(ph[e0 + e]) + bf2f(pl[e0 + e])) * bf2f(pb[e0 + e]);
        } else {
            const u16* ph = &skh[(rn - 32) * 264];
            const u16* pb = &wk[(rn - 32) * 264];
            for (int e = 0; e < 64; e++)
                s += bf2f(ph[e0 + e]) * bf2f(pb[e0 + e]);
        }
        redn[cc * 64 + rn] = s;
    }
    {
        int iq = w >> 1, jq = w & 1;
        f32x4 acc = {0.f, 0.f, 0.f, 0.f};
        for (int s8 = 0; s8 < 8; s8++) {
            bf16x8 a = *(const bf16x8*)&sqh[(iq * 16 + l15) * 264 + s8 * 32 + quad * 8];
            bf16x8 bb = *(const bf16x8*)&wk[(jq * 16 + l15) * 264 + s8 * 32 + quad * 8];
            acc = MFMA(a, bb, acc);
        }
        for (int s8 = 0; s8 < 8; s8++) {
            bf16x8 a = *(const bf16x8*)&sql[(iq * 16 + l15) * 264 + s8 * 32 + quad * 8];
            bf16x8 bb = *(const bf16x8*)&wk[(jq * 16 + l15) * 264 + s8 * 32 + quad * 8];
            acc = MFMA(a, bb, acc);
        }
        for (int r = 0; r < 4; r++)
            simS[(iq * 16 + quad * 4 + r) * 33 + jq * 16 + l15] = acc[r];
    }
    __syncthreads();
    if (t < 32)
        scq[t] = expf(temp[h]) * 8.0f /
                 fmaxf(sqrtf(redn[t] + redn[64 + t] + redn[128 + t] + redn[192 + t]), 1e-12f);
    else if (t < 64) {
        int d = t - 32;
        sck[d] = 1.0f / fmaxf(sqrtf(redn[32 + d] + redn[96 + d] + redn[160 + d] + redn[224 + d]), 1e-12f);
    }
    __syncthreads();
    if (t < 32) {
        float row[32];
        float m = -1e30f, sqv = scq[t];
#pragma unroll
        for (int j = 0; j < 32; j++) {
            float v = simS[t * 33 + j] * sqv * sck[j];
            row[j] = v; m = fmaxf(m, v);
        }
        float s = 0.f;
#pragma unroll
        for (int j = 0; j < 32; j++) { float p = expf(row[j] - m); row[j] = p; s += p; }
        float inv = 1.f / s;
#pragma unroll
        for (int j = 0; j < 32; j++) attnT[j * 40 + t] = f2bf(row[j] * inv);
    }
    __syncthreads();
    {
        f32x4 z = {0.f, 0.f, 0.f, 0.f};
        for (int mf = 0; mf < 4; mf++) {
            bf16x8 a = *(const bf16x8*)&wo[((w * 4 + mf) * 16 + l15) * 40 + quad * 8];
            for (int nf = 0; nf < 2; nf++) {
                bf16x8 bb = *(const bf16x8*)&attnT[(nf * 16 + l15) * 40 + quad * 8];
                f32x4 d = MFMA(a, bb, z);
                for (int r = 0; r < 4; r++) {
                    int c = (w * 4 + mf) * 16 + quad * 4 + r;
                    M_all[((size_t)(b * 256) + c) * 256 + h * 32 + nf * 16 + l15] = f2bf(d[r]);
                }
            }
        }
    }
}

extern "C" void kernel_launch(void* const* d_in, const int* in_sizes, int n_in,
                              void* d_out, int out_size, void* d_ws, size_t ws_size,
                              hipStream_t stream) {
    const float* x     = (const float*)d_in[0];
    const float* gamma = (const float*)d_in[1];
    const float* beta  = (const float*)d_in[2];
    const float* Wqkv  = (const float*)d_in[3];
    const float* temp  = (const float*)d_in[4];
    const float* Wout  = (const float*)d_in[5];
    const float* bout  = (const float*)d_in[6];
    float* out = (float*)d_out;

    char* ws = (char*)d_ws;
    size_t off = 0;
    auto alloc = [&](size_t nbytes) -> void* {
        void* p = ws + off;
        off = (off + nbytes + 255) & ~(size_t)255;
        return p;
    };
    u16* xlnT   = (u16*)alloc((size_t)16 * 4096 * 256 * 2);   // 32 MB (b,n,c)
    u16* WqkvT  = (u16*)alloc((size_t)512 * 256 * 2);
    u16* WvTn   = (u16*)alloc((size_t)256 * 256 * 2);
    u16* WoutT  = (u16*)alloc((size_t)256 * 256 * 2);
    float* Gp   = (float*)alloc((size_t)256 * 65536 * 4);     // 64 MB block partials
    u16* Gbh    = (u16*)alloc((size_t)16 * 65536 * 2);        // 2 MB
    u16* Gbl    = (u16*)alloc((size_t)16 * 65536 * 2);        // 2 MB
    u16* Sqh    = (u16*)alloc((size_t)16 * 512 * 256 * 2);    // 4 MB
    u16* Sql    = (u16*)alloc((size_t)16 * 512 * 256 * 2);    // 4 MB
    u16* M_all  = (u16*)alloc((size_t)16 * 256 * 256 * 2);    // 2 MB
    u16* F      = (u16*)alloc((size_t)16 * 256 * 256 * 2);    // 2 MB
    (void)ws_size; (void)in_sizes; (void)n_in; (void)out_size;

    hipLaunchKernelGGL(k_prep, dim3(1024), dim3(256), 0, stream, Wqkv, Wout, WqkvT, WvTn, WoutT);
    hipLaunchKernelGGL(k_lngram, dim3(256), dim3(1024), 0, stream, x, gamma, beta, xlnT, Gp);
    hipLaunchKernelGGL(k_g2b, dim3(1024), dim3(256), 0, stream, Gp, Gbh, Gbl);
    hipLaunchKernelGGL(k_sq, dim3(128), dim3(256), 0, stream, WqkvT, Gbh, Gbl, Sqh, Sql);
    hipLaunchKernelGGL(k_attn, dim3(128), dim3(256), 0, stream, Sqh, Sql, WqkvT, WoutT, temp, M_all);
    // F[b] = M_b (256x256) . Wv^T  (B-rows = WvTn rows)
    hipLaunchKernelGGL(k_gemm, dim3(64), dim3(256), 0, stream,
                       M_all, (size_t)65536, WvTn, (size_t)0, 2, 2,
                       F, (float*)nullptr, (const float*)nullptr,
                       (size_t)65536, 256, 0);
    // out[b] = F_b . X_b (+bias), BM=256
    hipLaunchKernelGGL(k_out, dim3(512), dim3(256), 0, stream, F, xlnT, bout, out);
}

// Round 7
// 241.951 us; speedup vs baseline: 1.1406x; 1.0558x over previous
//
#include <hip/hip_runtime.h>

typedef unsigned short u16;
typedef __bf16 bf16x8 __attribute__((ext_vector_type(8)));
typedef float f32x4 __attribute__((ext_vector_type(4)));

#define MFMA(a, b, c) __builtin_amdgcn_mfma_f32_16x16x32_bf16((a), (b), (c), 0, 0, 0)

__device__ __forceinline__ u16 f2bf(float f) {
    unsigned u = __float_as_uint(f);
    unsigned r = (u + 0x7fffu + ((u >> 16) & 1u)) >> 16;  // RNE
    return (u16)r;
}
__device__ __forceinline__ float bf2f(u16 h) { return __uint_as_float(((unsigned)h) << 16); }

typedef unsigned int u32_g __attribute__((address_space(1)));
typedef unsigned int u32_l __attribute__((address_space(3)));
__device__ __forceinline__ void gload16(const void* g, void* l) {
    __builtin_amdgcn_global_load_lds((const u32_g*)g, (u32_l*)l, 16, 0, 0);
}

// ---------------------------------------------------------------------------
// Shapes: b=16, c=256, n=4096, heads=8, dim_head=32
// Gram-trick pipeline; LN+Gram fused with c-slab split + reg-prefetch overlap.
// ---------------------------------------------------------------------------

// K1: fused LayerNorm + Gram slab partial.
// grid = 2 slabs * (16 b * 8 chunks) = 256 (slab is HIGH bits: partner at bid+-128
// lands on the same XCD -> x chunk L2-shared). block = 1024.
// Block (s, b, ch): n-range ch*512..+512 (4 sub-chunks of 128), G rows [s*128, s*128+128).
// Thread map: np = t&15 (n-pair), cgl = (t>>4)&15 (16 c each), g = t>>8 (n-subgroup).
// LDS 64KB time-shared: [stats] then [xst 256c x 64 pairs, slot-XOR swizzled
//   (HW-verified r5/r6): pair npg of row c at dword c*64 + (((npg>>2)^(c&15))<<2 | (npg&3))].
__global__ __launch_bounds__(1024) void k_lngram(const float* __restrict__ x,
                                                 const float* __restrict__ gamma,
                                                 const float* __restrict__ beta,
                                                 u16* __restrict__ xlnT, float* __restrict__ Gp) {
    __shared__ __align__(16) unsigned smem[256 * 64];  // 64 KB
    float* sf = (float*)smem;
    int bid = blockIdx.x;
    int s = bid >> 7;
    int bc = bid & 127;
    int b = bc >> 3, ch = bc & 7;
    int t = threadIdx.x;
    int np = t & 15, cgl = (t >> 4) & 15, g = t >> 8;
    int lane = t & 63, l15 = lane & 15, quad = lane >> 4;
    int w = t >> 6;
    int mr = w & 7, nh = w >> 3;
    int c0 = cgl * 16;
    int nl0 = g * 32 + 2 * np;  // even local n handled by this thread
    int npg = g * 16 + np;      // pair index 0..63
    int slot = npg >> 2, rem = npg & 3;
    f32x4 acc[8];
    {
        f32x4 z = {0.f, 0.f, 0.f, 0.f};
        for (int j = 0; j < 8; j++) acc[j] = z;
    }
    const float* xp = x + ((size_t)(b * 256 + c0)) * 4096 + ch * 512 + nl0;
    float2 v[16];
#pragma unroll
    for (int i = 0; i < 16; i++) v[i] = *(const float2*)(xp + (size_t)i * 4096);
    for (int sc = 0; sc < 4; sc++) {
        int nb = ch * 512 + sc * 128;
        float s0 = 0.f, s1 = 0.f, s20 = 0.f, s21 = 0.f;
#pragma unroll
        for (int i = 0; i < 16; i++) {
            float2 f = v[i];
            s0 += f.x; s20 += f.x * f.x;
            s1 += f.y; s21 += f.y * f.y;
        }
        if (sc) __syncthreads();  // prev MFMA done reading xst before stats overwrite
        sf[nl0 * 17 + cgl] = s0;
        sf[(nl0 + 1) * 17 + cgl] = s1;
        sf[2304 + nl0 * 17 + cgl] = s20;
        sf[2304 + (nl0 + 1) * 17 + cgl] = s21;
        __syncthreads();
        if (t < 128) {
            float a = 0.f, a2 = 0.f;
#pragma unroll
            for (int jj = 0; jj < 16; jj++) { a += sf[t * 17 + jj]; a2 += sf[2304 + t * 17 + jj]; }
            float m = a * (1.f / 256.f);
            float var = a2 * (1.f / 256.f) - m * m;
            sf[4608 + t] = m;
            sf[4800 + t] = rsqrtf(var + 1e-5f);
        }
        __syncthreads();
        float m0 = sf[4608 + nl0], r0 = sf[4800 + nl0];
        float m1 = sf[4608 + nl0 + 1], r1 = sf[4800 + nl0 + 1];
        __syncthreads();  // all mu/rs reads done before xst overwrites smem
        // P3: normalize in regs, write xst (swizzled) + xlnT (slab-gated, coalesced)
        u16 hA[16], hB[16];
#pragma unroll
        for (int i = 0; i < 16; i++) {
            int c = c0 + i;
            float ga = gamma[c], e = beta[c];
            float a = (v[i].x - m0) * r0 * ga + e;
            float bv = (v[i].y - m1) * r1 * ga + e;
            u16 ha = f2bf(a), hb = f2bf(bv);
            hA[i] = ha; hB[i] = hb;
            smem[c * 64 + (((slot ^ (c & 15)) << 2) | rem)] = (unsigned)ha | ((unsigned)hb << 16);
        }
        if ((cgl >> 3) == s) {
            u16* dst0 = xlnT + ((size_t)(b * 4096 + nb + nl0)) * 256 + c0;
            uint4 qa, qb;
            qa.x = (unsigned)hA[0] | ((unsigned)hA[1] << 16);
            qa.y = (unsigned)hA[2] | ((unsigned)hA[3] << 16);
            qa.z = (unsigned)hA[4] | ((unsigned)hA[5] << 16);
            qa.w = (unsigned)hA[6] | ((unsigned)hA[7] << 16);
            qb.x = (unsigned)hA[8] | ((unsigned)hA[9] << 16);
            qb.y = (unsigned)hA[10] | ((unsigned)hA[11] << 16);
            qb.z = (unsigned)hA[12] | ((unsigned)hA[13] << 16);
            qb.w = (unsigned)hA[14] | ((unsigned)hA[15] << 16);
            *(uint4*)dst0 = qa;
            *(uint4*)(dst0 + 8) = qb;
            u16* dst1 = dst0 + 256;
            qa.x = (unsigned)hB[0] | ((unsigned)hB[1] << 16);
            qa.y = (unsigned)hB[2] | ((unsigned)hB[3] << 16);
            qa.z = (unsigned)hB[4] | ((unsigned)hB[5] << 16);
            qa.w = (unsigned)hB[6] | ((unsigned)hB[7] << 16);
            qb.x = (unsigned)hB[8] | ((unsigned)hB[9] << 16);
            qb.y = (unsigned)hB[10] | ((unsigned)hB[11] << 16);
            qb.z = (unsigned)hB[12] | ((unsigned)hB[13] << 16);
            qb.w = (unsigned)hB[14] | ((unsigned)hB[15] << 16);
            *(uint4*)dst1 = qa;
            *(uint4*)(dst1 + 8) = qb;
        }
        __syncthreads();
        // prefetch next sub-chunk into the just-freed v[] -- overlaps the MFMA phase
        if (sc < 3) {
            const float* nxp = xp + (sc + 1) * 128;
#pragma unroll
            for (int i = 0; i < 16; i++) v[i] = *(const float2*)(nxp + (size_t)i * 4096);
        }
        // P4: Gram slab MFMA
        int ca = s * 128 + mr * 16 + l15;
#pragma unroll
        for (int ks = 0; ks < 4; ks++) {
            bf16x8 af = *(const bf16x8*)&smem[ca * 64 + (((ks * 4 + quad) ^ (ca & 15)) << 2)];
#pragma unroll
            for (int j = 0; j < 8; j++) {
                int cb = nh * 128 + j * 16 + l15;
                bf16x8 bb = *(const bf16x8*)&smem[cb * 64 + (((ks * 4 + quad) ^ (cb & 15)) << 2)];
                acc[j] = MFMA(af, bb, acc[j]);
            }
        }
    }
    // write block-private slab partial (non-atomic): [bid][128][256] fp32
    float* gp = Gp + (size_t)bid * 32768;
    for (int j = 0; j < 8; j++)
        for (int r = 0; r < 4; r++)
            gp[(mr * 16 + quad * 4 + r) * 256 + nh * 128 + j * 16 + l15] = acc[j][r];
}

// K2: fused weight prep + G reduce (8 partials) -> hi/lo bf16 split. grid 1024 x 256.
__global__ __launch_bounds__(256) void k_g2bp(const float* __restrict__ Gp,
                                              u16* __restrict__ Ghi, u16* __restrict__ Glo,
                                              const float* __restrict__ Wqkv,
                                              const float* __restrict__ Wout,
                                              u16* __restrict__ WqkvT, u16* __restrict__ WvTn,
                                              u16* __restrict__ WoutT) {
    int i = blockIdx.x * 256 + threadIdx.x;  // 0..262143
    if (i < 512 * 256) { int o = i >> 8, c = i & 255; WqkvT[i] = f2bf(Wqkv[c * 768 + o]); }
    if (i < 256 * 256) {
        int e = i >> 8, o = i & 255;
        WvTn[i] = f2bf(Wqkv[e * 768 + 512 + o]);
        WoutT[i] = f2bf(Wout[o * 256 + e]);
    }
    // G element block: i = b*16384 + row*64 + col4 (float4 granule)
    int b = i >> 14, e = i & 16383;
    int row = e >> 6, col4 = e & 63;
    int slab = row >> 7, rl = row & 127;
    const float4* p = (const float4*)(Gp + ((size_t)(slab * 128 + b * 8)) * 32768 + rl * 256 + col4 * 4);
    float4 sv = p[0];
#pragma unroll
    for (int jc = 1; jc < 8; jc++) {
        float4 vv = p[(size_t)jc * 8192];
        sv.x += vv.x; sv.y += vv.y; sv.z += vv.z; sv.w += vv.w;
    }
    u16 h0 = f2bf(sv.x), h1 = f2bf(sv.y), h2 = f2bf(sv.z), h3 = f2bf(sv.w);
    u16 l0 = f2bf(sv.x - bf2f(h0)), l1 = f2bf(sv.y - bf2f(h1));
    u16 l2 = f2bf(sv.z - bf2f(h2)), l3 = f2bf(sv.w - bf2f(h3));
    uint2 ph; ph.x = (unsigned)h0 | ((unsigned)h1 << 16); ph.y = (unsigned)h2 | ((unsigned)h3 << 16);
    uint2 pl; pl.x = (unsigned)l0 | ((unsigned)l1 << 16); pl.y = (unsigned)l2 | ((unsigned)l3 << 16);
    *(uint2*)(Ghi + (size_t)i * 4) = ph;
    *(uint2*)(Glo + (size_t)i * 4) = pl;
}

// K3: Sq = Wqk (512x256) . (Ghi + Glo), hi/lo output. grid = 16*8 = 128
__global__ __launch_bounds__(256) void k_sq(const u16* __restrict__ A,
                                            const u16* __restrict__ Ghi, const u16* __restrict__ Glo,
                                            u16* __restrict__ Shi, u16* __restrict__ Slo) {
    __shared__ __align__(16) u16 aT[128 * 32];
    __shared__ __align__(16) u16 bT[128 * 32];
    int bid = blockIdx.x;
    int b = bid >> 3;
    int r2 = bid & 7;
    int mbase = (r2 >> 1) * 128, nbase = (r2 & 1) * 128;
    int t = threadIdx.x, w = t >> 6, lane = t & 63, l15 = lane & 15, quad = lane >> 4;
    int srow = lane >> 2;
    int g8 = (((lane & 3) ^ ((lane >> 3) & 3)) << 3);
    const u16* gA = A + (size_t)(mbase + w * 32 + srow) * 256 + g8;
    const u16* gBh = Ghi + (size_t)b * 65536 + (size_t)(nbase + w * 32 + srow) * 256 + g8;
    const u16* gBl = Glo + (size_t)b * 65536 + (size_t)(nbase + w * 32 + srow) * 256 + g8;
    u16* lA = aT + w * 1024;
    u16* lB = bT + w * 1024;
    int cOff = ((quad ^ ((l15 >> 1) & 3)) << 3);
    f32x4 acc[2][8];
    f32x4 z = {0.f, 0.f, 0.f, 0.f};
    for (int fm = 0; fm < 2; fm++)
        for (int fn = 0; fn < 8; fn++) acc[fm][fn] = z;
    for (int kt = 0; kt < 16; kt++) {
        int kb = (kt & 7) * 32;
        const u16* gB = (kt < 8) ? gBh : gBl;
        if (kt) __syncthreads();
        gload16(gA + kb, lA);
        gload16(gA + 16 * 256 + kb, lA + 512);
        gload16(gB + kb, lB);
        gload16(gB + 16 * 256 + kb, lB + 512);
        __syncthreads();
        bf16x8 af0 = *(const bf16x8*)&aT[(w * 32 + l15) * 32 + cOff];
        bf16x8 af1 = *(const bf16x8*)&aT[(w * 32 + 16 + l15) * 32 + cOff];
        for (int fn = 0; fn < 8; fn++) {
            bf16x8 bfr = *(const bf16x8*)&bT[(fn * 16 + l15) * 32 + cOff];
            acc[0][fn] = MFMA(af0, bfr, acc[0][fn]);
            acc[1][fn] = MFMA(af1, bfr, acc[1][fn]);
        }
    }
    for (int fm = 0; fm < 2; fm++)
        for (int fn = 0; fn < 8; fn++)
            for (int r = 0; r < 4; r++) {
                int row = mbase + w * 32 + fm * 16 + quad * 4 + r;
                int col = nbase + fn * 16 + l15;
                float v = acc[fm][fn][r];
                u16 hi = f2bf(v);
                Shi[((size_t)b * 512 + row) * 256 + col] = hi;
                Slo[((size_t)b * 512 + row) * 256 + col] = f2bf(v - bf2f(hi));
            }
}

// K4: generic 128x128-tile GEMM, K=256 (used for F = M.Wv^T). mode 0: bf16 out.
__global__ __launch_bounds__(256) void k_gemm(const u16* __restrict__ A, size_t aStrB,
                                              const u16* __restrict__ Bb, size_t bStrB,
                                              int mtiles, int ntiles,
                                              u16* __restrict__ o16, float* __restrict__ o32,
                                              const float* __restrict__ bias,
                                              size_t oStrB, int oRstr, int mode) {
    __shared__ __align__(16) u16 aT[128 * 32];
    __shared__ __align__(16) u16 bT[128 * 32];
    int bid = blockIdx.x;
    int per_b = mtiles * ntiles;
    int b = bid / per_b;
    int r2 = bid % per_b;
    int mbase = (r2 / ntiles) * 128, nbase = (r2 % ntiles) * 128;
    int t = threadIdx.x, w = t >> 6, lane = t & 63, l15 = lane & 15, quad = lane >> 4;
    const u16* Ap = A + (size_t)b * aStrB;
    const u16* Bp = Bb + (size_t)b * bStrB;
    int srow = lane >> 2;
    int g8 = (((lane & 3) ^ ((lane >> 3) & 3)) << 3);
    const u16* gA = Ap + (size_t)(mbase + w * 32 + srow) * 256 + g8;
    const u16* gB = Bp + (size_t)(nbase + w * 32 + srow) * 256 + g8;
    u16* lA = aT + w * 1024;
    u16* lB = bT + w * 1024;
    int cOff = ((quad ^ ((l15 >> 1) & 3)) << 3);
    f32x4 acc[2][8];
    f32x4 z = {0.f, 0.f, 0.f, 0.f};
    for (int fm = 0; fm < 2; fm++)
        for (int fn = 0; fn < 8; fn++) acc[fm][fn] = z;
    for (int kt = 0; kt < 8; kt++) {
        int kb = kt * 32;
        if (kt) __syncthreads();
        gload16(gA + kb, lA);
        gload16(gA + 16 * 256 + kb, lA + 512);
        gload16(gB + kb, lB);
        gload16(gB + 16 * 256 + kb, lB + 512);
        __syncthreads();
        bf16x8 af0 = *(const bf16x8*)&aT[(w * 32 + l15) * 32 + cOff];
        bf16x8 af1 = *(const bf16x8*)&aT[(w * 32 + 16 + l15) * 32 + cOff];
        for (int fn = 0; fn < 8; fn++) {
            bf16x8 bfr = *(const bf16x8*)&bT[(fn * 16 + l15) * 32 + cOff];
            acc[0][fn] = MFMA(af0, bfr, acc[0][fn]);
            acc[1][fn] = MFMA(af1, bfr, acc[1][fn]);
        }
    }
    if (mode == 0) {
        for (int fm = 0; fm < 2; fm++)
            for (int fn = 0; fn < 8; fn++)
                for (int r = 0; r < 4; r++) {
                    int row = mbase + w * 32 + fm * 16 + quad * 4 + r;
                    int col = nbase + fn * 16 + l15;
                    o16[(size_t)b * oStrB + (size_t)row * oRstr + col] = f2bf(acc[fm][fn][r]);
                }
    } else {
        for (int fm = 0; fm < 2; fm++)
            for (int fn = 0; fn < 8; fn++)
                for (int r = 0; r < 4; r++) {
                    int row = mbase + w * 32 + fm * 16 + quad * 4 + r;
                    int col = nbase + fn * 16 + l15;
                    o32[(size_t)b * oStrB + (size_t)row * oRstr + col] = acc[fm][fn][r] + bias[row];
                }
    }
}

// K5: out = F (256x256) . X^T + bias, BM=256. grid = 512.
__global__ __launch_bounds__(256) void k_out(const u16* __restrict__ F, const u16* __restrict__ xlnT,
                                             const float* __restrict__ bias, float* __restrict__ out) {
    __shared__ __align__(16) u16 aT[256 * 32];
    __shared__ __align__(16) u16 bT[128 * 32];
    int bid = blockIdx.x;
    int b = bid >> 5, nt = bid & 31;
    int nbase = nt * 128;
    int t = threadIdx.x, w = t >> 6, lane = t & 63, l15 = lane & 15, quad = lane >> 4;
    int srow = lane >> 2;
    int g8 = (((lane & 3) ^ ((lane >> 3) & 3)) << 3);
    const u16* gA = F + (size_t)b * 65536 + (size_t)(w * 64 + srow) * 256 + g8;
    const u16* gB = xlnT + (size_t)b * 4096 * 256 + (size_t)(nbase + w * 32 + srow) * 256 + g8;
    u16* lA = aT + w * 2048;
    u16* lB = bT + w * 1024;
    int cOff = ((quad ^ ((l15 >> 1) & 3)) << 3);
    f32x4 acc[4][8];
    f32x4 z = {0.f, 0.f, 0.f, 0.f};
    for (int fm = 0; fm < 4; fm++)
        for (int fn = 0; fn < 8; fn++) acc[fm][fn] = z;
    for (int kt = 0; kt < 8; kt++) {
        int kb = kt * 32;
        if (kt) __syncthreads();
        gload16(gA + kb, lA);
        gload16(gA + 16 * 256 + kb, lA + 512);
        gload16(gA + 32 * 256 + kb, lA + 1024);
        gload16(gA + 48 * 256 + kb, lA + 1536);
        gload16(gB + kb, lB);
        gload16(gB + 16 * 256 + kb, lB + 512);
        __syncthreads();
        bf16x8 af[4];
#pragma unroll
        for (int fm = 0; fm < 4; fm++)
            af[fm] = *(const bf16x8*)&aT[(w * 64 + fm * 16 + l15) * 32 + cOff];
        for (int fn = 0; fn < 8; fn++) {
            bf16x8 bfr = *(const bf16x8*)&bT[(fn * 16 + l15) * 32 + cOff];
#pragma unroll
            for (int fm = 0; fm < 4; fm++) acc[fm][fn] = MFMA(af[fm], bfr, acc[fm][fn]);
        }
    }
    for (int fm = 0; fm < 4; fm++)
        for (int fn = 0; fn < 8; fn++)
            for (int r = 0; r < 4; r++) {
                int row = w * 64 + fm * 16 + quad * 4 + r;
                int col = nbase + fn * 16 + l15;
                out[((size_t)b * 256 + row) * 4096 + col] = acc[fm][fn][r] + bias[row];
            }
}

// K6: per (b,h): sim = (Sq_hi+Sq_lo) . Wk^T, norms from diag, softmax, M_h = wo.attn
__global__ __launch_bounds__(256) void k_attn(const u16* __restrict__ Shi,
                                              const u16* __restrict__ Slo,
                                              const u16* __restrict__ WqkvT,
                                              const u16* __restrict__ WoutT,
                                              const float* __restrict__ temp,
                                              u16* __restrict__ M_all) {
    int bh = blockIdx.x;
    int b = bh >> 3, h = bh & 7;
    __shared__ u16 sqh[32 * 264], sql[32 * 264], skh[32 * 264], wq[32 * 264], wk[32 * 264];
    __shared__ u16 wo[256 * 40];
    __shared__ u16 attnT[32 * 40];
    __shared__ float simS[32 * 33];
    __shared__ float redn[4 * 64];
    __shared__ float scq[32], sck[32];
    int t = threadIdx.x, w = t >> 6, lane = t & 63, l15 = lane & 15, quad = lane >> 4;
    {
        int r = t >> 3, cc0 = (t & 7) * 32;
        const u16* gqh = Shi + ((size_t)(b * 512) + h * 32 + r) * 256 + cc0;
        const u16* gql = Slo + ((size_t)(b * 512) + h * 32 + r) * 256 + cc0;
        const u16* gkh = Shi + ((size_t)(b * 512) + 256 + h * 32 + r) * 256 + cc0;
        const u16* gwq = WqkvT + (size_t)(h * 32 + r) * 256 + cc0;
        const u16* gwk = WqkvT + (size_t)(256 + h * 32 + r) * 256 + cc0;
#pragma unroll
        for (int k = 0; k < 4; k++) {
            *(uint4*)&sqh[r * 264 + cc0 + k * 8] = *(const uint4*)(gqh + k * 8);
            *(uint4*)&sql[r * 264 + cc0 + k * 8] = *(const uint4*)(gql + k * 8);
            *(uint4*)&skh[r * 264 + cc0 + k * 8] = *(const uint4*)(gkh + k * 8);
            *(uint4*)&wq[r * 264 + cc0 + k * 8] = *(const uint4*)(gwq + k * 8);
            *(uint4*)&wk[r * 264 + cc0 + k * 8] = *(const uint4*)(gwk + k * 8);
        }
        const u16* gwo = WoutT + (size_t)t * 256 + h * 32;
#pragma unroll
        for (int k = 0; k < 4; k++) *(uint4*)&wo[t * 40 + k * 8] = *(const uint4*)(gwo + k * 8);
    }
    __syncthreads();
    {
        int rn = t & 63, cc = t >> 6;
        int e0 = cc * 64;
        float s = 0.f;
        if (rn < 32) {
            const u16* ph = &sqh[rn * 264];
            const u16* pl = &sql[rn * 264];
            const u16* pb = &wq[rn * 264];
            for (int e = 0; e < 64; e++)
                s += (bf2f(ph[e0 + e]) + bf2f(pl[e0 + e])) * bf2f(pb[e0 + e]);
        } else {
            const u16* ph = &skh[(rn - 32) * 264];
            const u16* pb = &wk[(rn - 32) * 264];
            for (int e = 0; e < 64; e++)
                s += bf2f(ph[e0 + e]) * bf2f(pb[e0 + e]);
        }
        redn[cc * 64 + rn] = s;
    }
    {
        int iq = w >> 1, jq = w & 1;
        f32x4 acc = {0.f, 0.f, 0.f, 0.f};
        for (int s8 = 0; s8 < 8; s8++) {
            bf16x8 a = *(const bf16x8*)&sqh[(iq * 16 + l15) * 264 + s8 * 32 + quad * 8];
            bf16x8 bb = *(const bf16x8*)&wk[(jq * 16 + l15) * 264 + s8 * 32 + quad * 8];
            acc = MFMA(a, bb, acc);
        }
        for (int s8 = 0; s8 < 8; s8++) {
            bf16x8 a = *(const bf16x8*)&sql[(iq * 16 + l15) * 264 + s8 * 32 + quad * 8];
            bf16x8 bb = *(const bf16x8*)&wk[(jq * 16 + l15) * 264 + s8 * 32 + quad * 8];
            acc = MFMA(a, bb, acc);
        }
        for (int r = 0; r < 4; r++)
            simS[(iq * 16 + quad * 4 + r) * 33 + jq * 16 + l15] = acc[r];
    }
    __syncthreads();
    if (t < 32)
        scq[t] = expf(temp[h]) * 8.0f /
                 fmaxf(sqrtf(redn[t] + redn[64 + t] + redn[128 + t] + redn[192 + t]), 1e-12f);
    else if (t < 64) {
        int d = t - 32;
        sck[d] = 1.0f / fmaxf(sqrtf(redn[32 + d] + redn[96 + d] + redn[160 + d] + redn[224 + d]), 1e-12f);
    }
    __syncthreads();
    if (t < 32) {
        float row[32];
        float m = -1e30f, sqv = scq[t];
#pragma unroll
        for (int j = 0; j < 32; j++) {
            float v = simS[t * 33 + j] * sqv * sck[j];
            row[j] = v; m = fmaxf(m, v);
        }
        float s = 0.f;
#pragma unroll
        for (int j = 0; j < 32; j++) { float p = expf(row[j] - m); row[j] = p; s += p; }
        float inv = 1.f / s;
#pragma unroll
        for (int j = 0; j < 32; j++) attnT[j * 40 + t] = f2bf(row[j] * inv);
    }
    __syncthreads();
    {
        f32x4 z = {0.f, 0.f, 0.f, 0.f};
        for (int mf = 0; mf < 4; mf++) {
            bf16x8 a = *(const bf16x8*)&wo[((w * 4 + mf) * 16 + l15) * 40 + quad * 8];
            for (int nf = 0; nf < 2; nf++) {
                bf16x8 bb = *(const bf16x8*)&attnT[(nf * 16 + l15) * 40 + quad * 8];
                f32x4 d = MFMA(a, bb, z);
                for (int r = 0; r < 4; r++) {
                    int c = (w * 4 + mf) * 16 + quad * 4 + r;
                    M_all[((size_t)(b * 256) + c) * 256 + h * 32 + nf * 16 + l15] = f2bf(d[r]);
                }
            }
        }
    }
}

extern "C" void kernel_launch(void* const* d_in, const int* in_sizes, int n_in,
                              void* d_out, int out_size, void* d_ws, size_t ws_size,
                              hipStream_t stream) {
    const float* x     = (const float*)d_in[0];
    const float* gamma = (const float*)d_in[1];
    const float* beta  = (const float*)d_in[2];
    const float* Wqkv  = (const float*)d_in[3];
    const float* temp  = (const float*)d_in[4];
    const float* Wout  = (const float*)d_in[5];
    const float* bout  = (const float*)d_in[6];
    float* out = (float*)d_out;

    char* ws = (char*)d_ws;
    size_t off = 0;
    auto alloc = [&](size_t nbytes) -> void* {
        void* p = ws + off;
        off = (off + nbytes + 255) & ~(size_t)255;
        return p;
    };
    u16* xlnT   = (u16*)alloc((size_t)16 * 4096 * 256 * 2);   // 32 MB (b,n,c)
    u16* WqkvT  = (u16*)alloc((size_t)512 * 256 * 2);
    u16* WvTn   = (u16*)alloc((size_t)256 * 256 * 2);
    u16* WoutT  = (u16*)alloc((size_t)256 * 256 * 2);
    float* Gp   = (float*)alloc((size_t)256 * 32768 * 4);     // 32 MB slab partials
    u16* Gbh    = (u16*)alloc((size_t)16 * 65536 * 2);        // 2 MB
    u16* Gbl    = (u16*)alloc((size_t)16 * 65536 * 2);        // 2 MB
    u16* Sqh    = (u16*)alloc((size_t)16 * 512 * 256 * 2);    // 4 MB
    u16* Sql    = (u16*)alloc((size_t)16 * 512 * 256 * 2);    // 4 MB
    u16* M_all  = (u16*)alloc((size_t)16 * 256 * 256 * 2);    // 2 MB
    u16* F      = (u16*)alloc((size_t)16 * 256 * 256 * 2);    // 2 MB
    (void)ws_size; (void)in_sizes; (void)n_in; (void)out_size;

    hipLaunchKernelGGL(k_lngram, dim3(256), dim3(1024), 0, stream, x, gamma, beta, xlnT, Gp);
    hipLaunchKernelGGL(k_g2bp, dim3(1024), dim3(256), 0, stream, Gp, Gbh, Gbl,
                       Wqkv, Wout, WqkvT, WvTn, WoutT);
    hipLaunchKernelGGL(k_sq, dim3(128), dim3(256), 0, stream, WqkvT, Gbh, Gbl, Sqh, Sql);
    hipLaunchKernelGGL(k_attn, dim3(128), dim3(256), 0, stream, Sqh, Sql, WqkvT, WoutT, temp, M_all);
    // F[b] = M_b (256x256) . Wv^T  (B-rows = WvTn rows)
    hipLaunchKernelGGL(k_gemm, dim3(64), dim3(256), 0, stream,
                       M_all, (size_t)65536, WvTn, (size_t)0, 2, 2,
                       F, (float*)nullptr, (const float*)nullptr,
                       (size_t)65536, 256, 0);
    // out[b] = F_b . X_b (+bias), BM=256
    hipLaunchKernelGGL(k_out, dim3(512), dim3(256), 0, stream, F, xlnT, bout, out);
}

// Round 8
// 220.780 us; speedup vs baseline: 1.2500x; 1.0959x over previous
//
#include <hip/hip_runtime.h>

typedef unsigned short u16;
typedef __bf16 bf16x8 __attribute__((ext_vector_type(8)));
typedef float f32x4 __attribute__((ext_vector_type(4)));

#define MFMA(a, b, c) __builtin_amdgcn_mfma_f32_16x16x32_bf16((a), (b), (c), 0, 0, 0)

__device__ __forceinline__ u16 f2bf(float f) {
    unsigned u = __float_as_uint(f);
    unsigned r = (u + 0x7fffu + ((u >> 16) & 1u)) >> 16;  // RNE
    return (u16)r;
}
__device__ __forceinline__ float bf2f(u16 h) { return __uint_as_float(((unsigned)h) << 16); }

typedef unsigned int u32_g __attribute__((address_space(1)));
typedef unsigned int u32_l __attribute__((address_space(3)));
__device__ __forceinline__ void gload16(const void* g, void* l) {
    __builtin_amdgcn_global_load_lds((const u32_g*)g, (u32_l*)l, 16, 0, 0);
}

// ---------------------------------------------------------------------------
// Shapes: b=16, c=256, n=4096, heads=8, dim_head=32
// Gram-trick pipeline, SPLIT structure (round-3 proven best), consolidated.
// ---------------------------------------------------------------------------

// K1: LayerNorm, register-resident (round-4 proven). x (b,c,n) fp32 ->
// xlnT (b,n,c) bf16 AND xcn (b,c,n) bf16. 32 n per block, grid = 2048.
__global__ __launch_bounds__(256) void k_ln(const float* __restrict__ x,
                                            const float* __restrict__ gamma,
                                            const float* __restrict__ beta,
                                            u16* __restrict__ xlnT, u16* __restrict__ xcn) {
    int bid = blockIdx.x;
    int b = bid >> 7, nt = bid & 127;
    int nb = nt * 32;
    __shared__ float redS[32 * 17], redS2[32 * 17];
    __shared__ float muv[32], rsv[32];
    __shared__ float gs[256], es[256];
    __shared__ unsigned xst[256 * 17];
    int t = threadIdx.x;
    int np = t & 15, cg = t >> 4;
    gs[t] = gamma[t];
    es[t] = beta[t];
    const float* xp = x + ((size_t)(b * 256 + cg * 16)) * 4096 + nb + np * 2;
    float2 v[16];
    float s0 = 0.f, s1 = 0.f, s20 = 0.f, s21 = 0.f;
#pragma unroll
    for (int i = 0; i < 16; i++) {
        float2 f = *(const float2*)(xp + (size_t)i * 4096);
        v[i] = f;
        s0 += f.x; s20 += f.x * f.x;
        s1 += f.y; s21 += f.y * f.y;
    }
    redS[(2 * np) * 17 + cg] = s0;
    redS[(2 * np + 1) * 17 + cg] = s1;
    redS2[(2 * np) * 17 + cg] = s20;
    redS2[(2 * np + 1) * 17 + cg] = s21;
    __syncthreads();
    if (t < 32) {
        float s = 0.f, s2 = 0.f;
#pragma unroll
        for (int g = 0; g < 16; g++) { s += redS[t * 17 + g]; s2 += redS2[t * 17 + g]; }
        float m = s * (1.f / 256.f);
        float var = s2 * (1.f / 256.f) - m * m;
        muv[t] = m;
        rsv[t] = rsqrtf(var + 1e-5f);
    }
    __syncthreads();
    float m0 = muv[2 * np], r0 = rsv[2 * np];
    float m1 = muv[2 * np + 1], r1 = rsv[2 * np + 1];
    u16 hA[16], hB[16];
#pragma unroll
    for (int i = 0; i < 16; i++) {
        float g = gs[cg * 16 + i], e = es[cg * 16 + i];
        float a = (v[i].x - m0) * r0 * g + e;
        float c2 = (v[i].y - m1) * r1 * g + e;
        u16 ha = f2bf(a), hb = f2bf(c2);
        hA[i] = ha; hB[i] = hb;
        xst[(cg * 16 + i) * 17 + np] = (unsigned)ha | ((unsigned)hb << 16);
    }
    {
        u16* dst0 = xlnT + ((size_t)(b * 4096 + nb + 2 * np)) * 256 + cg * 16;
        uint4 qa, qb;
        qa.x = (unsigned)hA[0] | ((unsigned)hA[1] << 16);
        qa.y = (unsigned)hA[2] | ((unsigned)hA[3] << 16);
        qa.z = (unsigned)hA[4] | ((unsigned)hA[5] << 16);
        qa.w = (unsigned)hA[6] | ((unsigned)hA[7] << 16);
        qb.x = (unsigned)hA[8] | ((unsigned)hA[9] << 16);
        qb.y = (unsigned)hA[10] | ((unsigned)hA[11] << 16);
        qb.z = (unsigned)hA[12] | ((unsigned)hA[13] << 16);
        qb.w = (unsigned)hA[14] | ((unsigned)hA[15] << 16);
        *(uint4*)dst0 = qa;
        *(uint4*)(dst0 + 8) = qb;
        u16* dst1 = dst0 + 256;
        qa.x = (unsigned)hB[0] | ((unsigned)hB[1] << 16);
        qa.y = (unsigned)hB[2] | ((unsigned)hB[3] << 16);
        qa.z = (unsigned)hB[4] | ((unsigned)hB[5] << 16);
        qa.w = (unsigned)hB[6] | ((unsigned)hB[7] << 16);
        qb.x = (unsigned)hB[8] | ((unsigned)hB[9] << 16);
        qb.y = (unsigned)hB[10] | ((unsigned)hB[11] << 16);
        qb.z = (unsigned)hB[12] | ((unsigned)hB[13] << 16);
        qb.w = (unsigned)hB[14] | ((unsigned)hB[15] << 16);
        *(uint4*)dst1 = qa;
        *(uint4*)(dst1 + 8) = qb;
    }
    __syncthreads();
#pragma unroll
    for (int j = 0; j < 4; j++) {
        int row = (t >> 2) + j * 64, part = t & 3;
        uint4 q;
        q.x = xst[row * 17 + part * 4 + 0];
        q.y = xst[row * 17 + part * 4 + 1];
        q.z = xst[row * 17 + part * 4 + 2];
        q.w = xst[row * 17 + part * 4 + 3];
        *(uint4*)(xcn + ((size_t)(b * 256 + row)) * 4096 + nb + part * 8) = q;
    }
}

// K2: Gram partials (round-3 proven). Gp[s][b] = X . X^T over n in [s*512, s*512+512)
// grid = 16 b * 4 tiles * 8 splits = 512.
__global__ __launch_bounds__(256) void k_gram(const u16* __restrict__ xcn, float* __restrict__ Gp) {
    int bid = blockIdx.x;
    int s = bid & 7, tile = (bid >> 3) & 3, b = bid >> 5;
    int tm = tile >> 1, tn = tile & 1;
    __shared__ __align__(16) u16 aT[128 * 32];
    __shared__ __align__(16) u16 bT[128 * 32];
    int t = threadIdx.x, w = t >> 6, lane = t & 63, l15 = lane & 15, quad = lane >> 4;
    int srow = lane >> 2;
    int g8 = (((lane & 3) ^ ((lane >> 3) & 3)) << 3);
    const u16* xb = xcn + (size_t)b * 256 * 4096 + (size_t)s * 512;
    const u16* gA = xb + (size_t)(tm * 128 + w * 32 + srow) * 4096 + g8;
    const u16* gB = xb + (size_t)(tn * 128 + w * 32 + srow) * 4096 + g8;
    u16* lA = aT + w * 1024;
    u16* lB = bT + w * 1024;
    int cOff = ((quad ^ ((l15 >> 1) & 3)) << 3);
    f32x4 acc[2][8];
    f32x4 z = {0.f, 0.f, 0.f, 0.f};
    for (int fm = 0; fm < 2; fm++)
        for (int fn = 0; fn < 8; fn++) acc[fm][fn] = z;
    for (int kt = 0; kt < 16; kt++) {
        int kb = kt * 32;
        if (kt) __syncthreads();
        gload16(gA + kb, lA);
        gload16(gA + 16 * 4096 + kb, lA + 512);
        gload16(gB + kb, lB);
        gload16(gB + 16 * 4096 + kb, lB + 512);
        __syncthreads();
        bf16x8 af0 = *(const bf16x8*)&aT[(w * 32 + l15) * 32 + cOff];
        bf16x8 af1 = *(const bf16x8*)&aT[(w * 32 + 16 + l15) * 32 + cOff];
        for (int fn = 0; fn < 8; fn++) {
            bf16x8 bfr = *(const bf16x8*)&bT[(fn * 16 + l15) * 32 + cOff];
            acc[0][fn] = MFMA(af0, bfr, acc[0][fn]);
            acc[1][fn] = MFMA(af1, bfr, acc[1][fn]);
        }
    }
    float* gp = Gp + (size_t)(s * 16 + b) * 65536;
    for (int fm = 0; fm < 2; fm++)
        for (int fn = 0; fn < 8; fn++)
            for (int r = 0; r < 4; r++) {
                int row = tm * 128 + w * 32 + fm * 16 + quad * 4 + r;
                int col = tn * 128 + fn * 16 + l15;
                gp[row * 256 + col] = acc[fm][fn][r];
            }
}

// K3: fused weight prep + G reduce (8 partials, round-3 layout) -> hi/lo bf16.
// grid 1024 x 256.
__global__ __launch_bounds__(256) void k_g2bp(const float* __restrict__ Gp,
                                              u16* __restrict__ Ghi, u16* __restrict__ Glo,
                                              const float* __restrict__ Wqkv,
                                              const float* __restrict__ Wout,
                                              u16* __restrict__ WqkvT, u16* __restrict__ WvTn,
                                              u16* __restrict__ WoutT) {
    int i = blockIdx.x * 256 + threadIdx.x;  // 0..262143
    if (i < 512 * 256) { int o = i >> 8, c = i & 255; WqkvT[i] = f2bf(Wqkv[c * 768 + o]); }
    if (i < 256 * 256) {
        int e = i >> 8, o = i & 255;
        WvTn[i] = f2bf(Wqkv[e * 768 + 512 + o]);
        WoutT[i] = f2bf(Wout[o * 256 + e]);
    }
    // G reduce: i indexes float4 granules of [16 b][16384]; partial stride = 16*16384 float4s
    const float4* p = (const float4*)Gp + i;
    float4 s = p[0];
#pragma unroll
    for (int j = 1; j < 8; j++) {
        float4 v = p[(size_t)j * 262144];
        s.x += v.x; s.y += v.y; s.z += v.z; s.w += v.w;
    }
    u16 h0 = f2bf(s.x), h1 = f2bf(s.y), h2 = f2bf(s.z), h3 = f2bf(s.w);
    u16 l0 = f2bf(s.x - bf2f(h0)), l1 = f2bf(s.y - bf2f(h1));
    u16 l2 = f2bf(s.z - bf2f(h2)), l3 = f2bf(s.w - bf2f(h3));
    uint2 ph; ph.x = (unsigned)h0 | ((unsigned)h1 << 16); ph.y = (unsigned)h2 | ((unsigned)h3 << 16);
    uint2 pl; pl.x = (unsigned)l0 | ((unsigned)l1 << 16); pl.y = (unsigned)l2 | ((unsigned)l3 << 16);
    *(uint2*)(Ghi + (size_t)i * 4) = ph;
    *(uint2*)(Glo + (size_t)i * 4) = pl;
}

// K4: Sq = Wqk (512x256) . (Ghi + Glo), hi/lo output. grid = 16*8 = 128
__global__ __launch_bounds__(256) void k_sq(const u16* __restrict__ A,
                                            const u16* __restrict__ Ghi, const u16* __restrict__ Glo,
                                            u16* __restrict__ Shi, u16* __restrict__ Slo) {
    __shared__ __align__(16) u16 aT[128 * 32];
    __shared__ __align__(16) u16 bT[128 * 32];
    int bid = blockIdx.x;
    int b = bid >> 3;
    int r2 = bid & 7;
    int mbase = (r2 >> 1) * 128, nbase = (r2 & 1) * 128;
    int t = threadIdx.x, w = t >> 6, lane = t & 63, l15 = lane & 15, quad = lane >> 4;
    int srow = lane >> 2;
    int g8 = (((lane & 3) ^ ((lane >> 3) & 3)) << 3);
    const u16* gA = A + (size_t)(mbase + w * 32 + srow) * 256 + g8;
    const u16* gBh = Ghi + (size_t)b * 65536 + (size_t)(nbase + w * 32 + srow) * 256 + g8;
    const u16* gBl = Glo + (size_t)b * 65536 + (size_t)(nbase + w * 32 + srow) * 256 + g8;
    u16* lA = aT + w * 1024;
    u16* lB = bT + w * 1024;
    int cOff = ((quad ^ ((l15 >> 1) & 3)) << 3);
    f32x4 acc[2][8];
    f32x4 z = {0.f, 0.f, 0.f, 0.f};
    for (int fm = 0; fm < 2; fm++)
        for (int fn = 0; fn < 8; fn++) acc[fm][fn] = z;
    for (int kt = 0; kt < 16; kt++) {
        int kb = (kt & 7) * 32;
        const u16* gB = (kt < 8) ? gBh : gBl;
        if (kt) __syncthreads();
        gload16(gA + kb, lA);
        gload16(gA + 16 * 256 + kb, lA + 512);
        gload16(gB + kb, lB);
        gload16(gB + 16 * 256 + kb, lB + 512);
        __syncthreads();
        bf16x8 af0 = *(const bf16x8*)&aT[(w * 32 + l15) * 32 + cOff];
        bf16x8 af1 = *(const bf16x8*)&aT[(w * 32 + 16 + l15) * 32 + cOff];
        for (int fn = 0; fn < 8; fn++) {
            bf16x8 bfr = *(const bf16x8*)&bT[(fn * 16 + l15) * 32 + cOff];
            acc[0][fn] = MFMA(af0, bfr, acc[0][fn]);
            acc[1][fn] = MFMA(af1, bfr, acc[1][fn]);
        }
    }
    for (int fm = 0; fm < 2; fm++)
        for (int fn = 0; fn < 8; fn++)
            for (int r = 0; r < 4; r++) {
                int row = mbase + w * 32 + fm * 16 + quad * 4 + r;
                int col = nbase + fn * 16 + l15;
                float v = acc[fm][fn][r];
                u16 hi = f2bf(v);
                Shi[((size_t)b * 512 + row) * 256 + col] = hi;
                Slo[((size_t)b * 512 + row) * 256 + col] = f2bf(v - bf2f(hi));
            }
}

// K5: generic 128x128-tile GEMM, K=256 (used for F = M.Wv^T). mode 0: bf16 out.
__global__ __launch_bounds__(256) void k_gemm(const u16* __restrict__ A, size_t aStrB,
                                              const u16* __restrict__ Bb, size_t bStrB,
                                              int mtiles, int ntiles,
                                              u16* __restrict__ o16, float* __restrict__ o32,
                                              const float* __restrict__ bias,
                                              size_t oStrB, int oRstr, int mode) {
    __shared__ __align__(16) u16 aT[128 * 32];
    __shared__ __align__(16) u16 bT[128 * 32];
    int bid = blockIdx.x;
    int per_b = mtiles * ntiles;
    int b = bid / per_b;
    int r2 = bid % per_b;
    int mbase = (r2 / ntiles) * 128, nbase = (r2 % ntiles) * 128;
    int t = threadIdx.x, w = t >> 6, lane = t & 63, l15 = lane & 15, quad = lane >> 4;
    const u16* Ap = A + (size_t)b * aStrB;
    const u16* Bp = Bb + (size_t)b * bStrB;
    int srow = lane >> 2;
    int g8 = (((lane & 3) ^ ((lane >> 3) & 3)) << 3);
    const u16* gA = Ap + (size_t)(mbase + w * 32 + srow) * 256 + g8;
    const u16* gB = Bp + (size_t)(nbase + w * 32 + srow) * 256 + g8;
    u16* lA = aT + w * 1024;
    u16* lB = bT + w * 1024;
    int cOff = ((quad ^ ((l15 >> 1) & 3)) << 3);
    f32x4 acc[2][8];
    f32x4 z = {0.f, 0.f, 0.f, 0.f};
    for (int fm = 0; fm < 2; fm++)
        for (int fn = 0; fn < 8; fn++) acc[fm][fn] = z;
    for (int kt = 0; kt < 8; kt++) {
        int kb = kt * 32;
        if (kt) __syncthreads();
        gload16(gA + kb, lA);
        gload16(gA + 16 * 256 + kb, lA + 512);
        gload16(gB + kb, lB);
        gload16(gB + 16 * 256 + kb, lB + 512);
        __syncthreads();
        bf16x8 af0 = *(const bf16x8*)&aT[(w * 32 + l15) * 32 + cOff];
        bf16x8 af1 = *(const bf16x8*)&aT[(w * 32 + 16 + l15) * 32 + cOff];
        for (int fn = 0; fn < 8; fn++) {
            bf16x8 bfr = *(const bf16x8*)&bT[(fn * 16 + l15) * 32 + cOff];
            acc[0][fn] = MFMA(af0, bfr, acc[0][fn]);
            acc[1][fn] = MFMA(af1, bfr, acc[1][fn]);
        }
    }
    if (mode == 0) {
        for (int fm = 0; fm < 2; fm++)
            for (int fn = 0; fn < 8; fn++)
                for (int r = 0; r < 4; r++) {
                    int row = mbase + w * 32 + fm * 16 + quad * 4 + r;
                    int col = nbase + fn * 16 + l15;
                    o16[(size_t)b * oStrB + (size_t)row * oRstr + col] = f2bf(acc[fm][fn][r]);
                }
    } else {
        for (int fm = 0; fm < 2; fm++)
            for (int fn = 0; fn < 8; fn++)
                for (int r = 0; r < 4; r++) {
                    int row = mbase + w * 32 + fm * 16 + quad * 4 + r;
                    int col = nbase + fn * 16 + l15;
                    o32[(size_t)b * oStrB + (size_t)row * oRstr + col] = acc[fm][fn][r] + bias[row];
                }
    }
}

// K6: out = F (256x256) . X^T + bias, BM=256 (B panel read once). grid = 512.
__global__ __launch_bounds__(256) void k_out(const u16* __restrict__ F, const u16* __restrict__ xlnT,
                                             const float* __restrict__ bias, float* __restrict__ out) {
    __shared__ __align__(16) u16 aT[256 * 32];
    __shared__ __align__(16) u16 bT[128 * 32];
    int bid = blockIdx.x;
    int b = bid >> 5, nt = bid & 31;
    int nbase = nt * 128;
    int t = threadIdx.x, w = t >> 6, lane = t & 63, l15 = lane & 15, quad = lane >> 4;
    int srow = lane >> 2;
    int g8 = (((lane & 3) ^ ((lane >> 3) & 3)) << 3);
    const u16* gA = F + (size_t)b * 65536 + (size_t)(w * 64 + srow) * 256 + g8;
    const u16* gB = xlnT + (size_t)b * 4096 * 256 + (size_t)(nbase + w * 32 + srow) * 256 + g8;
    u16* lA = aT + w * 2048;
    u16* lB = bT + w * 1024;
    int cOff = ((quad ^ ((l15 >> 1) & 3)) << 3);
    f32x4 acc[4][8];
    f32x4 z = {0.f, 0.f, 0.f, 0.f};
    for (int fm = 0; fm < 4; fm++)
        for (int fn = 0; fn < 8; fn++) acc[fm][fn] = z;
    for (int kt = 0; kt < 8; kt++) {
        int kb = kt * 32;
        if (kt) __syncthreads();
        gload16(gA + kb, lA);
        gload16(gA + 16 * 256 + kb, lA + 512);
        gload16(gA + 32 * 256 + kb, lA + 1024);
        gload16(gA + 48 * 256 + kb, lA + 1536);
        gload16(gB + kb, lB);
        gload16(gB + 16 * 256 + kb, lB + 512);
        __syncthreads();
        bf16x8 af[4];
#pragma unroll
        for (int fm = 0; fm < 4; fm++)
            af[fm] = *(const bf16x8*)&aT[(w * 64 + fm * 16 + l15) * 32 + cOff];
        for (int fn = 0; fn < 8; fn++) {
            bf16x8 bfr = *(const bf16x8*)&bT[(fn * 16 + l15) * 32 + cOff];
#pragma unroll
            for (int fm = 0; fm < 4; fm++) acc[fm][fn] = MFMA(af[fm], bfr, acc[fm][fn]);
        }
    }
    for (int fm = 0; fm < 4; fm++)
        for (int fn = 0; fn < 8; fn++)
            for (int r = 0; r < 4; r++) {
                int row = w * 64 + fm * 16 + quad * 4 + r;
                int col = nbase + fn * 16 + l15;
                out[((size_t)b * 256 + row) * 4096 + col] = acc[fm][fn][r] + bias[row];
            }
}

// K7: per (b,h): sim = (Sq_hi+Sq_lo) . Wk^T, norms from diag, softmax, M_h = wo.attn
__global__ __launch_bounds__(256) void k_attn(const u16* __restrict__ Shi,
                                              const u16* __restrict__ Slo,
                                              const u16* __restrict__ WqkvT,
                                              const u16* __restrict__ WoutT,
                                              const float* __restrict__ temp,
                                              u16* __restrict__ M_all) {
    int bh = blockIdx.x;
    int b = bh >> 3, h = bh & 7;
    __shared__ u16 sqh[32 * 264], sql[32 * 264], skh[32 * 264], wq[32 * 264], wk[32 * 264];
    __shared__ u16 wo[256 * 40];
    __shared__ u16 attnT[32 * 40];
    __shared__ float simS[32 * 33];
    __shared__ float redn[4 * 64];
    __shared__ float scq[32], sck[32];
    int t = threadIdx.x, w = t >> 6, lane = t & 63, l15 = lane & 15, quad = lane >> 4;
    {
        int r = t >> 3, cc0 = (t & 7) * 32;
        const u16* gqh = Shi + ((size_t)(b * 512) + h * 32 + r) * 256 + cc0;
        const u16* gql = Slo + ((size_t)(b * 512) + h * 32 + r) * 256 + cc0;
        const u16* gkh = Shi + ((size_t)(b * 512) + 256 + h * 32 + r) * 256 + cc0;
        const u16* gwq = WqkvT + (size_t)(h * 32 + r) * 256 + cc0;
        const u16* gwk = WqkvT + (size_t)(256 + h * 32 + r) * 256 + cc0;
#pragma unroll
        for (int k = 0; k < 4; k++) {
            *(uint4*)&sqh[r * 264 + cc0 + k * 8] = *(const uint4*)(gqh + k * 8);
            *(uint4*)&sql[r * 264 + cc0 + k * 8] = *(const uint4*)(gql + k * 8);
            *(uint4*)&skh[r * 264 + cc0 + k * 8] = *(const uint4*)(gkh + k * 8);
            *(uint4*)&wq[r * 264 + cc0 + k * 8] = *(const uint4*)(gwq + k * 8);
            *(uint4*)&wk[r * 264 + cc0 + k * 8] = *(const uint4*)(gwk + k * 8);
        }
        const u16* gwo = WoutT + (size_t)t * 256 + h * 32;
#pragma unroll
        for (int k = 0; k < 4; k++) *(uint4*)&wo[t * 40 + k * 8] = *(const uint4*)(gwo + k * 8);
    }
    __syncthreads();
    {
        int rn = t & 63, cc = t >> 6;
        int e0 = cc * 64;
        float s = 0.f;
        if (rn < 32) {
            const u16* ph = &sqh[rn * 264];
            const u16* pl = &sql[rn * 264];
            const u16* pb = &wq[rn * 264];
            for (int e = 0; e < 64; e++)
                s += (bf2f(ph[e0 + e]) + bf2f(pl[e0 + e])) * bf2f(pb[e0 + e]);
        } else {
            const u16* ph = &skh[(rn - 32) * 264];
            const u16* pb = &wk[(rn - 32) * 264];
            for (int e = 0; e < 64; e++)
                s += bf2f(ph[e0 + e]) * bf2f(pb[e0 + e]);
        }
        redn[cc * 64 + rn] = s;
    }
    {
        int iq = w >> 1, jq = w & 1;
        f32x4 acc = {0.f, 0.f, 0.f, 0.f};
        for (int s8 = 0; s8 < 8; s8++) {
            bf16x8 a = *(const bf16x8*)&sqh[(iq * 16 + l15) * 264 + s8 * 32 + quad * 8];
            bf16x8 bb = *(const bf16x8*)&wk[(jq * 16 + l15) * 264 + s8 * 32 + quad * 8];
            acc = MFMA(a, bb, acc);
        }
        for (int s8 = 0; s8 < 8; s8++) {
            bf16x8 a = *(const bf16x8*)&sql[(iq * 16 + l15) * 264 + s8 * 32 + quad * 8];
            bf16x8 bb = *(const bf16x8*)&wk[(jq * 16 + l15) * 264 + s8 * 32 + quad * 8];
            acc = MFMA(a, bb, acc);
        }
        for (int r = 0; r < 4; r++)
            simS[(iq * 16 + quad * 4 + r) * 33 + jq * 16 + l15] = acc[r];
    }
    __syncthreads();
    if (t < 32)
        scq[t] = expf(temp[h]) * 8.0f /
                 fmaxf(sqrtf(redn[t] + redn[64 + t] + redn[128 + t] + redn[192 + t]), 1e-12f);
    else if (t < 64) {
        int d = t - 32;
        sck[d] = 1.0f / fmaxf(sqrtf(redn[32 + d] + redn[96 + d] + redn[160 + d] + redn[224 + d]), 1e-12f);
    }
    __syncthreads();
    if (t < 32) {
        float row[32];
        float m = -1e30f, sqv = scq[t];
#pragma unroll
        for (int j = 0; j < 32; j++) {
            float v = simS[t * 33 + j] * sqv * sck[j];
            row[j] = v; m = fmaxf(m, v);
        }
        float s = 0.f;
#pragma unroll
        for (int j = 0; j < 32; j++) { float p = expf(row[j] - m); row[j] = p; s += p; }
        float inv = 1.f / s;
#pragma unroll
        for (int j = 0; j < 32; j++) attnT[j * 40 + t] = f2bf(row[j] * inv);
    }
    __syncthreads();
    {
        f32x4 z = {0.f, 0.f, 0.f, 0.f};
        for (int mf = 0; mf < 4; mf++) {
            bf16x8 a = *(const bf16x8*)&wo[((w * 4 + mf) * 16 + l15) * 40 + quad * 8];
            for (int nf = 0; nf < 2; nf++) {
                bf16x8 bb = *(const bf16x8*)&attnT[(nf * 16 + l15) * 40 + quad * 8];
                f32x4 d = MFMA(a, bb, z);
                for (int r = 0; r < 4; r++) {
                    int c = (w * 4 + mf) * 16 + quad * 4 + r;
                    M_all[((size_t)(b * 256) + c) * 256 + h * 32 + nf * 16 + l15] = f2bf(d[r]);
                }
            }
        }
    }
}

extern "C" void kernel_launch(void* const* d_in, const int* in_sizes, int n_in,
                              void* d_out, int out_size, void* d_ws, size_t ws_size,
                              hipStream_t stream) {
    const float* x     = (const float*)d_in[0];
    const float* gamma = (const float*)d_in[1];
    const float* beta  = (const float*)d_in[2];
    const float* Wqkv  = (const float*)d_in[3];
    const float* temp  = (const float*)d_in[4];
    const float* Wout  = (const float*)d_in[5];
    const float* bout  = (const float*)d_in[6];
    float* out = (float*)d_out;

    char* ws = (char*)d_ws;
    size_t off = 0;
    auto alloc = [&](size_t nbytes) -> void* {
        void* p = ws + off;
        off = (off + nbytes + 255) & ~(size_t)255;
        return p;
    };
    u16* xlnT   = (u16*)alloc((size_t)16 * 4096 * 256 * 2);   // 32 MB (b,n,c)
    u16* xcn    = (u16*)alloc((size_t)16 * 256 * 4096 * 2);   // 32 MB (b,c,n)
    u16* WqkvT  = (u16*)alloc((size_t)512 * 256 * 2);
    u16* WvTn   = (u16*)alloc((size_t)256 * 256 * 2);
    u16* WoutT  = (u16*)alloc((size_t)256 * 256 * 2);
    float* Gp   = (float*)alloc((size_t)8 * 16 * 65536 * 4);  // 32 MB split partials
    u16* Gbh    = (u16*)alloc((size_t)16 * 65536 * 2);        // 2 MB
    u16* Gbl    = (u16*)alloc((size_t)16 * 65536 * 2);        // 2 MB
    u16* Sqh    = (u16*)alloc((size_t)16 * 512 * 256 * 2);    // 4 MB
    u16* Sql    = (u16*)alloc((size_t)16 * 512 * 256 * 2);    // 4 MB
    u16* M_all  = (u16*)alloc((size_t)16 * 256 * 256 * 2);    // 2 MB
    u16* F      = (u16*)alloc((size_t)16 * 256 * 256 * 2);    // 2 MB
    (void)ws_size; (void)in_sizes; (void)n_in; (void)out_size;

    hipLaunchKernelGGL(k_ln, dim3(2048), dim3(256), 0, stream, x, gamma, beta, xlnT, xcn);
    hipLaunchKernelGGL(k_gram, dim3(512), dim3(256), 0, stream, xcn, Gp);
    hipLaunchKernelGGL(k_g2bp, dim3(1024), dim3(256), 0, stream, Gp, Gbh, Gbl,
                       Wqkv, Wout, WqkvT, WvTn, WoutT);
    hipLaunchKernelGGL(k_sq, dim3(128), dim3(256), 0, stream, WqkvT, Gbh, Gbl, Sqh, Sql);
    hipLaunchKernelGGL(k_attn, dim3(128), dim3(256), 0, stream, Sqh, Sql, WqkvT, WoutT, temp, M_all);
    // F[b] = M_b (256x256) . Wv^T  (B-rows = WvTn rows)
    hipLaunchKernelGGL(k_gemm, dim3(64), dim3(256), 0, stream,
                       M_all, (size_t)65536, WvTn, (size_t)0, 2, 2,
                       F, (float*)nullptr, (const float*)nullptr,
                       (size_t)65536, 256, 0);
    // out[b] = F_b . X_b (+bias), BM=256
    hipLaunchKernelGGL(k_out, dim3(512), dim3(256), 0, stream, F, xlnT, bout, out);
}